// Round 10
// baseline (490.212 us; speedup 1.0000x reference)
//
#include <hip/hip_runtime.h>
#include <math.h>

// ---------------------------------------------------------------------------
// GAT forward (3 layers) on MI355X. N=50000, D=128, H=2, k=64.
// E=800000 real edges + N self-loops (Et=850000).
// Round 10: GEMM moved to matrix cores via bf16x3 (fp32-accurate) emulation:
// W pre-split into 3 bf16 planes (wsplit), A split during LDS staging,
// 6 cross-product MFMAs (16x16x32) per tile. Attention dots fused in epilogue
// via small LDS reduce. Everything else identical to round 9.
// ---------------------------------------------------------------------------

#define EPB 8192   // edges per coarse block

typedef __attribute__((ext_vector_type(8))) short short8v;
typedef __attribute__((ext_vector_type(4))) short short4v;
typedef __attribute__((ext_vector_type(4))) float f32x4;

// ---- W -> 3 bf16 planes (per layer, 128x128) ------------------------------
__global__ __launch_bounds__(256) void wsplit(const float* __restrict__ Wm,
                                              unsigned short* __restrict__ Wb) {
    int i = blockIdx.x * 256 + threadIdx.x;
    if (i >= 16384) return;
    float v = Wm[i];
    unsigned int u = __float_as_uint(v);
    unsigned int h1 = (u + 0x7FFFu + ((u >> 16) & 1u)) >> 16;
    float r = v - __uint_as_float(h1 << 16);
    unsigned int u2 = __float_as_uint(r);
    unsigned int h2 = (u2 + 0x7FFFu + ((u2 >> 16) & 1u)) >> 16;
    float r2 = r - __uint_as_float(h2 << 16);
    unsigned int u3 = __float_as_uint(r2);
    unsigned int h3 = (u3 + 0x7FFFu + ((u3 >> 16) & 1u)) >> 16;
    Wb[i] = (unsigned short)h1;
    Wb[16384 + i] = (unsigned short)h2;
    Wb[32768 + i] = (unsigned short)h3;
}

// ---- MFMA GEMM: C = A(N x 128) @ W^T, fp32-accurate via bf16x3 ------------
// Block: 256 thr (4 waves), 64-row tile. Wave w owns coltiles {2w, 2w+1}
// (cols w*32..w*32+31) across all 4 rowtiles. K in 4 chunks of 32.
#define APL 8704    // 64*136 (A plane stride, shorts)
#define WPL 16896   // 128*132 (W plane stride, shorts)
__global__ __launch_bounds__(256) void gemm_mfma(const float* __restrict__ A,
                                                 const unsigned short* __restrict__ Wb,
                                                 const float* __restrict__ att,
                                                 float* __restrict__ C,
                                                 float4* __restrict__ ni4,
                                                 float2* __restrict__ ad2v, int N) {
    __shared__ unsigned short AL[3 * APL];   // A bf16x3, [p][64][136]
    __shared__ unsigned short WL[3 * WPL];   // W bf16x3, [p][128][132]
    __shared__ float SR[4][64][2];           // per-wave {pd, ps} partials
    const int tx = threadIdx.x;
    const int row0 = blockIdx.x * 64;
    const float4* A4 = (const float4*)A;

    // stage A (64 x 128 f32) -> 3 bf16 planes
    for (int i = tx; i < 2048; i += 256) {
        int r = i >> 5, q = i & 31;
        int row = row0 + r;
        float4 v = (row < N) ? A4[(size_t)row * 32 + q] : make_float4(0.f, 0.f, 0.f, 0.f);
        float e[4] = {v.x, v.y, v.z, v.w};
        unsigned int h1[4], h2[4], h3[4];
        #pragma unroll
        for (int j = 0; j < 4; ++j) {
            unsigned int u = __float_as_uint(e[j]);
            h1[j] = (u + 0x7FFFu + ((u >> 16) & 1u)) >> 16;
            float r1 = e[j] - __uint_as_float(h1[j] << 16);
            unsigned int u2 = __float_as_uint(r1);
            h2[j] = (u2 + 0x7FFFu + ((u2 >> 16) & 1u)) >> 16;
            float r2 = r1 - __uint_as_float(h2[j] << 16);
            unsigned int u3 = __float_as_uint(r2);
            h3[j] = (u3 + 0x7FFFu + ((u3 >> 16) & 1u)) >> 16;
        }
        int base = r * 136 + q * 4;
        *(uint2*)&AL[0 * APL + base] = make_uint2(h1[0] | (h1[1] << 16), h1[2] | (h1[3] << 16));
        *(uint2*)&AL[1 * APL + base] = make_uint2(h2[0] | (h2[1] << 16), h2[2] | (h2[3] << 16));
        *(uint2*)&AL[2 * APL + base] = make_uint2(h3[0] | (h3[1] << 16), h3[2] | (h3[3] << 16));
    }
    // stage W planes (pre-split): [p][col][k] -> padded LDS
    for (int i = tx; i < 12288; i += 256) {   // 3*128*32 uint2 chunks
        int p = i >> 12, rem = i & 4095;
        int col = rem >> 5, q = rem & 31;
        uint2 v = ((const uint2*)Wb)[i];
        *(uint2*)&WL[p * WPL + col * 132 + q * 4] = v;
    }
    __syncthreads();

    const int lane = tx & 63;
    const int wid = tx >> 6;
    const int cl = lane & 15;
    const int kg = lane >> 4;

    f32x4 acc[2][4];
    #pragma unroll
    for (int cc = 0; cc < 2; ++cc)
        #pragma unroll
        for (int rt = 0; rt < 4; ++rt)
            acc[cc][rt] = (f32x4){0.f, 0.f, 0.f, 0.f};

    for (int kk = 0; kk < 4; ++kk) {
        short8v af[4][3];
        #pragma unroll
        for (int rt = 0; rt < 4; ++rt)
            #pragma unroll
            for (int p = 0; p < 3; ++p)
                af[rt][p] = *(const short8v*)&AL[p * APL + (rt * 16 + cl) * 136 + kk * 32 + kg * 8];
        short8v bfr[2][3];
        #pragma unroll
        for (int cc = 0; cc < 2; ++cc) {
            int col = wid * 32 + cc * 16 + cl;
            #pragma unroll
            for (int p = 0; p < 3; ++p) {
                int base = p * WPL + col * 132 + kk * 32 + kg * 8;
                short4v b0 = *(const short4v*)&WL[base];
                short4v b1 = *(const short4v*)&WL[base + 4];
                short8v b;
                b[0] = b0[0]; b[1] = b0[1]; b[2] = b0[2]; b[3] = b0[3];
                b[4] = b1[0]; b[5] = b1[1]; b[6] = b1[2]; b[7] = b1[3];
                bfr[cc][p] = b;
            }
        }
        #pragma unroll
        for (int cc = 0; cc < 2; ++cc)
            #pragma unroll
            for (int rt = 0; rt < 4; ++rt) {
                f32x4 a = acc[cc][rt];
                a = __builtin_amdgcn_mfma_f32_16x16x32_bf16(af[rt][0], bfr[cc][0], a, 0, 0, 0);
                a = __builtin_amdgcn_mfma_f32_16x16x32_bf16(af[rt][0], bfr[cc][1], a, 0, 0, 0);
                a = __builtin_amdgcn_mfma_f32_16x16x32_bf16(af[rt][1], bfr[cc][0], a, 0, 0, 0);
                a = __builtin_amdgcn_mfma_f32_16x16x32_bf16(af[rt][0], bfr[cc][2], a, 0, 0, 0);
                a = __builtin_amdgcn_mfma_f32_16x16x32_bf16(af[rt][1], bfr[cc][1], a, 0, 0, 0);
                a = __builtin_amdgcn_mfma_f32_16x16x32_bf16(af[rt][2], bfr[cc][0], a, 0, 0, 0);
                acc[cc][rt] = a;
            }
    }

    // C store: thread holds C[row0+rt*16+kg*4+r][wid*32+cc*16+cl]
    #pragma unroll
    for (int cc = 0; cc < 2; ++cc)
        #pragma unroll
        for (int rt = 0; rt < 4; ++rt)
            #pragma unroll
            for (int r = 0; r < 4; ++r) {
                int row = row0 + rt * 16 + kg * 4 + r;
                if (row < N) C[(size_t)row * 128 + wid * 32 + cc * 16 + cl] = acc[cc][rt][r];
            }

    // fused attention dots: head hh = wid>>1, feat f = (wid&1)*32 + cc*16 + cl
    const int hh = wid >> 1;
    float attd0 = att[hh * 128 + (wid & 1) * 32 + cl];
    float attd1 = att[hh * 128 + (wid & 1) * 32 + 16 + cl];
    float atts0 = att[hh * 128 + 64 + (wid & 1) * 32 + cl];
    float atts1 = att[hh * 128 + 64 + (wid & 1) * 32 + 16 + cl];
    #pragma unroll
    for (int rt = 0; rt < 4; ++rt) {
        float pd[4], ps[4];
        #pragma unroll
        for (int r = 0; r < 4; ++r) {
            pd[r] = acc[0][rt][r] * attd0 + acc[1][rt][r] * attd1;
            ps[r] = acc[0][rt][r] * atts0 + acc[1][rt][r] * atts1;
        }
        #pragma unroll
        for (int m = 1; m < 16; m <<= 1) {
            #pragma unroll
            for (int r = 0; r < 4; ++r) {
                pd[r] += __shfl_xor(pd[r], m);
                ps[r] += __shfl_xor(ps[r], m);
            }
        }
        if (cl == 0) {
            #pragma unroll
            for (int r = 0; r < 4; ++r) {
                int rl = rt * 16 + kg * 4 + r;
                SR[wid][rl][0] = pd[r];
                SR[wid][rl][1] = ps[r];
            }
        }
    }
    __syncthreads();
    if (tx < 64) {
        int row = row0 + tx;
        if (row < N) {
            float pd0 = SR[0][tx][0] + SR[1][tx][0];
            float ps0 = SR[0][tx][1] + SR[1][tx][1];
            float pd1 = SR[2][tx][0] + SR[3][tx][0];
            float ps1 = SR[2][tx][1] + SR[3][tx][1];
            ad2v[row] = make_float2(pd0, pd1);
            ni4[row] = make_float4(ps0, ps1, 0.f, 0.f);
        }
    }
}

// ----------------------- 2-level CSR build (once) --------------------------
__global__ __launch_bounds__(512) void coarse_hist(const int* __restrict__ ei, int E, int Et,
                                                   unsigned int* __restrict__ gh_d,
                                                   unsigned int* __restrict__ gh_s, int CB) {
    __shared__ unsigned int lh_d[800];
    __shared__ unsigned int lh_s[800];
    const int t = threadIdx.x;
    for (int b = t; b < CB; b += 512) { lh_d[b] = 0u; lh_s[b] = 0u; }
    __syncthreads();
    const int i0 = blockIdx.x * EPB;
    for (int i = t; i < EPB; i += 512) {
        int e = i0 + i;
        if (e < Et) {
            int s, d;
            if (e < E) { s = ei[e]; d = ei[E + e]; } else { s = d = e - E; }
            atomicAdd(&lh_d[d >> 6], 1u);
            atomicAdd(&lh_s[s >> 6], 1u);
        }
    }
    __syncthreads();
    for (int b = t; b < CB; b += 512) {
        if (lh_d[b]) atomicAdd(&gh_d[b], lh_d[b]);
        if (lh_s[b]) atomicAdd(&gh_s[b], lh_s[b]);
    }
}

__global__ __launch_bounds__(1024) void coarse_scan(const unsigned int* __restrict__ gh_d,
                                                    const unsigned int* __restrict__ gh_s,
                                                    unsigned int* __restrict__ coff_d,
                                                    unsigned int* __restrict__ coff_s,
                                                    unsigned int* __restrict__ cur_d,
                                                    unsigned int* __restrict__ cur_s,
                                                    int CB, unsigned int total) {
    __shared__ unsigned int sh[1024];
    const int t = threadIdx.x;
    for (int a = 0; a < 2; ++a) {
        const unsigned int* gh = a ? gh_s : gh_d;
        unsigned int* coff = a ? coff_s : coff_d;
        unsigned int* cur  = a ? cur_s : cur_d;
        sh[t] = (t < CB) ? gh[t] : 0u;
        __syncthreads();
        #pragma unroll
        for (int d = 1; d < 1024; d <<= 1) {
            unsigned int u = (t >= d) ? sh[t - d] : 0u;
            __syncthreads();
            sh[t] += u;
            __syncthreads();
        }
        if (t < CB) {
            unsigned int ex = (t == 0) ? 0u : sh[t - 1];
            coff[t] = ex;
            cur[t] = ex;
        }
        if (t == 0) coff[CB] = total;
        __syncthreads();
    }
}

__global__ __launch_bounds__(512) void coarse_scatter_both(const int* __restrict__ ei,
                                                           int E, int Et,
                                                           unsigned int* __restrict__ cur_d,
                                                           unsigned int* __restrict__ cur_s,
                                                           unsigned int* __restrict__ tmp_d,
                                                           unsigned int* __restrict__ tmp_s,
                                                           int CB) {
    __shared__ unsigned int lh_d[800];
    __shared__ unsigned int lh_s[800];
    const int t = threadIdx.x;
    for (int b = t; b < CB; b += 512) { lh_d[b] = 0u; lh_s[b] = 0u; }
    __syncthreads();
    const int i0 = blockIdx.x * EPB;
    for (int i = t; i < EPB; i += 512) {
        int e = i0 + i;
        if (e < Et) {
            int s, d;
            if (e < E) { s = ei[e]; d = ei[E + e]; } else { s = d = e - E; }
            atomicAdd(&lh_d[d >> 6], 1u);
            atomicAdd(&lh_s[s >> 6], 1u);
        }
    }
    __syncthreads();
    for (int b = t; b < CB; b += 512) {
        unsigned int cd = lh_d[b], cs = lh_s[b];
        lh_d[b] = cd ? atomicAdd(&cur_d[b], cd) : 0u;
        lh_s[b] = cs ? atomicAdd(&cur_s[b], cs) : 0u;
    }
    __syncthreads();
    for (int i = t; i < EPB; i += 512) {
        int e = i0 + i;
        if (e < Et) {
            int s, d;
            if (e < E) { s = ei[e]; d = ei[E + e]; } else { s = d = e - E; }
            unsigned int pd = atomicAdd(&lh_d[d >> 6], 1u);
            tmp_d[pd] = ((unsigned int)(d & 63) << 16) | (unsigned int)s;
            unsigned int ps = atomicAdd(&lh_s[s >> 6], 1u);
            tmp_s[ps] = ((unsigned int)(s & 63) << 16) | (unsigned int)d;
        }
    }
}

__global__ __launch_bounds__(256) void fine_sort(const unsigned int* __restrict__ tmp_d,
                                                 const unsigned int* __restrict__ tmp_s,
                                                 const unsigned int* __restrict__ coff_d,
                                                 const unsigned int* __restrict__ coff_s,
                                                 unsigned int* __restrict__ off_d,
                                                 unsigned int* __restrict__ off_s,
                                                 int* __restrict__ srcs,
                                                 int* __restrict__ dsts,
                                                 int N, int CB, unsigned int total) {
    __shared__ unsigned int cnt[64];
    __shared__ unsigned int h[64];
    const bool isS = (int)blockIdx.x >= CB;
    const int b = isS ? (blockIdx.x - CB) : blockIdx.x;
    const unsigned int* tmp  = isS ? tmp_s : tmp_d;
    const unsigned int* coff = isS ? coff_s : coff_d;
    unsigned int* off = isS ? off_s : off_d;
    int* outv = isS ? dsts : srcs;
    const int node0 = b * 64;
    int nn = N - node0; if (nn > 64) nn = 64;
    const int t = threadIdx.x;
    const unsigned int cb0 = coff[b], cb1 = coff[b + 1];
    if (t < 64) cnt[t] = 0u;
    __syncthreads();
    for (unsigned int i = cb0 + t; i < cb1; i += 256)
        atomicAdd(&cnt[tmp[i] >> 16], 1u);
    __syncthreads();
    if (t < 64) h[t] = cnt[t];
    __syncthreads();
    #pragma unroll
    for (int d = 1; d < 64; d <<= 1) {
        unsigned int u = (t < 64 && t >= d) ? h[t - d] : 0u;
        __syncthreads();
        if (t < 64) h[t] += u;
        __syncthreads();
    }
    if (t < 64) h[t] = cb0 + h[t] - cnt[t];
    __syncthreads();
    if (t < nn) off[node0 + t] = h[t];
    if (b == CB - 1 && t == 0) off[N] = total;
    for (unsigned int i = cb0 + t; i < cb1; i += 256) {
        unsigned int v = tmp[i];
        unsigned int pos = atomicAdd(&h[v >> 16], 1u);
        outv[pos] = (int)(v & 0xFFFFu);
    }
}

// ---- softmax denominator per src node: gather a_dst over out-edges --------
__global__ __launch_bounds__(256) void src_sum(const int* __restrict__ dsts,
                                               const unsigned int* __restrict__ off_s,
                                               const float2* __restrict__ ad2,
                                               float* __restrict__ ni, int N) {
    int n = blockIdx.x * 256 + threadIdx.x;
    if (n >= N) return;
    float as0 = ni[(size_t)n * 4 + 0];
    float as1 = ni[(size_t)n * 4 + 1];
    unsigned int j0 = off_s[n], j1 = off_s[n + 1];
    float s0 = 0.f, s1 = 0.f;
    unsigned int j = j0;
    for (; j + 4 <= j1; j += 4) {
        int d0 = dsts[j], d1 = dsts[j + 1], d2 = dsts[j + 2], d3 = dsts[j + 3];
        float2 a0 = ad2[d0], a1 = ad2[d1], a2 = ad2[d2], a3 = ad2[d3];
        float t;
        t = as0 + a0.x; t = (t > 0.f) ? t : 0.2f * t; s0 += __expf(t);
        t = as1 + a0.y; t = (t > 0.f) ? t : 0.2f * t; s1 += __expf(t);
        t = as0 + a1.x; t = (t > 0.f) ? t : 0.2f * t; s0 += __expf(t);
        t = as1 + a1.y; t = (t > 0.f) ? t : 0.2f * t; s1 += __expf(t);
        t = as0 + a2.x; t = (t > 0.f) ? t : 0.2f * t; s0 += __expf(t);
        t = as1 + a2.y; t = (t > 0.f) ? t : 0.2f * t; s1 += __expf(t);
        t = as0 + a3.x; t = (t > 0.f) ? t : 0.2f * t; s0 += __expf(t);
        t = as1 + a3.y; t = (t > 0.f) ? t : 0.2f * t; s1 += __expf(t);
    }
    for (; j < j1; ++j) {
        float2 a = ad2[dsts[j]];
        float t;
        t = as0 + a.x; t = (t > 0.f) ? t : 0.2f * t; s0 += __expf(t);
        t = as1 + a.y; t = (t > 0.f) ? t : 0.2f * t; s1 += __expf(t);
    }
    ni[(size_t)n * 4 + 2] = 1.0f / (s0 + 1e-16f);
    ni[(size_t)n * 4 + 3] = 1.0f / (s1 + 1e-16f);
}

// ---- per-edge weights in dst-CSR order ------------------------------------
__global__ __launch_bounds__(256) void edge_w(const int* __restrict__ srcs,
                                              const unsigned int* __restrict__ off_d,
                                              const float4* __restrict__ ni4,
                                              const float2* __restrict__ ad2,
                                              float2* __restrict__ w2, int N) {
    __shared__ unsigned int lb[65];
    __shared__ float2 lad[64];
    const int node0 = blockIdx.x * 64;
    int nn = N - node0; if (nn > 64) nn = 64;
    const int t = threadIdx.x;
    if (t <= nn) lb[t] = off_d[node0 + t];
    if (t < nn) lad[t] = ad2[node0 + t];
    __syncthreads();
    unsigned int base = lb[0], end = lb[nn];
    for (unsigned int i = base + t; i < end; i += 256) {
        int lo = 0, hi = nn;
        while (hi - lo > 1) {
            int mid = (lo + hi) >> 1;
            if (i >= lb[mid]) lo = mid; else hi = mid;
        }
        float2 ad = lad[lo];
        int s = srcs[i];
        float4 nv = ni4[s];
        float a0 = ad.x + nv.x; a0 = (a0 > 0.f) ? a0 : 0.2f * a0;
        float a1 = ad.y + nv.y; a1 = (a1 > 0.f) ? a1 : 0.2f * a1;
        w2[i] = make_float2(__expf(a0) * nv.z, __expf(a1) * nv.w);
    }
}

// ---------------- CSR aggregation: one wave per dst node -------------------
template <int U>
__device__ __forceinline__ void agg_edges(unsigned int j, const int* __restrict__ srcs,
                                          const float2* __restrict__ w2,
                                          const float2* __restrict__ x2,
                                          int l, int hi, float& accx, float& accy) {
    int s[U]; float2 w[U]; float2 v[U];
    #pragma unroll
    for (int u = 0; u < U; ++u) s[u] = srcs[j + u];
    #pragma unroll
    for (int u = 0; u < U; ++u) w[u] = w2[j + u];
    #pragma unroll
    for (int u = 0; u < U; ++u) v[u] = x2[(size_t)s[u] * 64 + l];
    #pragma unroll
    for (int u = 0; u < U; ++u) {
        float ww = hi ? w[u].y : w[u].x;
        accx += v[u].x * ww;
        accy += v[u].y * ww;
    }
}

template <bool LAST>
__global__ __launch_bounds__(256) void agg_csr(const int* __restrict__ srcs,
                                               const unsigned int* __restrict__ off,
                                               const float2* __restrict__ x2,
                                               const float2* __restrict__ w2,
                                               const float* __restrict__ bias,
                                               float* __restrict__ out,
                                               const float* __restrict__ Wout,
                                               const float* __restrict__ bout,
                                               float* __restrict__ out3,
                                               float* __restrict__ ypred, int N) {
    int d = blockIdx.x * 4 + (threadIdx.x >> 6);
    int l = threadIdx.x & 63;
    if (d >= N) return;
    d = __builtin_amdgcn_readfirstlane(d);
    const int hi = l >> 5;
    unsigned int j0 = off[d], j1 = off[d + 1];
    float accx = 0.f, accy = 0.f;
    unsigned int j = j0;
    for (; j + 16 <= j1; j += 16) agg_edges<16>(j, srcs, w2, x2, l, hi, accx, accy);
    if (j + 8 <= j1) { agg_edges<8>(j, srcs, w2, x2, l, hi, accx, accy); j += 8; }
    if (j + 4 <= j1) { agg_edges<4>(j, srcs, w2, x2, l, hi, accx, accy); j += 4; }
    if (j + 2 <= j1) { agg_edges<2>(j, srcs, w2, x2, l, hi, accx, accy); j += 2; }
    if (j < j1)      { agg_edges<1>(j, srcs, w2, x2, l, hi, accx, accy); }

    float2 bb = ((const float2*)bias)[l];
    float o0 = fmaxf(accx + bb.x, 0.f);
    float o1 = fmaxf(accy + bb.y, 0.f);
    ((float2*)out)[(size_t)d * 64 + l] = make_float2(o0, o1);
    if (LAST) {
        const float2* W2 = (const float2*)Wout;
        float2 wa = W2[l], wb = W2[64 + l], wc = W2[128 + l];
        float p0 = o0 * wa.x + o1 * wa.y;
        float p1 = o0 * wb.x + o1 * wb.y;
        float p2 = o0 * wc.x + o1 * wc.y;
        #pragma unroll
        for (int m = 32; m; m >>= 1) {
            p0 += __shfl_xor(p0, m);
            p1 += __shfl_xor(p1, m);
            p2 += __shfl_xor(p2, m);
        }
        if (l == 0) {
            p0 += bout[0]; p1 += bout[1]; p2 += bout[2];
            out3[d * 3 + 0] = p0; out3[d * 3 + 1] = p1; out3[d * 3 + 2] = p2;
            int am = 0; float best = p0;
            if (p1 > best) { best = p1; am = 1; }
            if (p2 > best) { best = p2; am = 2; }
            ypred[d] = (float)am;
        }
    }
}

__global__ __launch_bounds__(256) void gather_out(const float* __restrict__ out3,
                                                  const float* __restrict__ ypred,
                                                  const int* __restrict__ node_index,
                                                  float* __restrict__ node_out,
                                                  float* __restrict__ y_nodepred, int M) {
    int i = blockIdx.x * 256 + threadIdx.x;
    if (i >= M) return;
    int idx = node_index[i];
    node_out[i * 3 + 0] = out3[idx * 3 + 0];
    node_out[i * 3 + 1] = out3[idx * 3 + 1];
    node_out[i * 3 + 2] = out3[idx * 3 + 2];
    y_nodepred[i] = ypred[idx];
}

extern "C" void kernel_launch(void* const* d_in, const int* in_sizes, int n_in,
                              void* d_out, int out_size, void* d_ws, size_t ws_size,
                              hipStream_t stream) {
    const float* x          = (const float*)d_in[0];
    const int*   ei         = (const int*)d_in[1];
    const int*   node_index = (const int*)d_in[3];
    const float* W[3]   = {(const float*)d_in[4], (const float*)d_in[7], (const float*)d_in[10]};
    const float* att[3] = {(const float*)d_in[5], (const float*)d_in[8], (const float*)d_in[11]};
    const float* b[3]   = {(const float*)d_in[6], (const float*)d_in[9], (const float*)d_in[12]};
    const float* Wout = (const float*)d_in[13];
    const float* bout = (const float*)d_in[14];

    const int N  = in_sizes[0] / 128;
    const int E  = in_sizes[1] / 2;
    const int Et = E + N;
    const int M  = in_sizes[3];
    const int CB = (N + 63) / 64;            // coarse buckets (782)
    const int NBLK = (Et + EPB - 1) / EPB;   // coarse blocks (104)

    // workspace layout (floats), ~66 MB.
    float* ws     = (float*)d_ws;
    float* xlin   = ws;                               // N*128
    unsigned int* tmp_d = (unsigned int*)ws;          // Et (build only)
    unsigned int* tmp_s = tmp_d + (size_t)Et;         // Et (build only)
    float* hb     = xlin + (size_t)N * 128;           // N*128
    float* ad     = hb + (size_t)N * 128;             // N*2  (a_dst)
    float* ni     = ad + (size_t)N * 2;               // N*4  {as0,as1,rcp0,rcp1}
    float* out3   = ad;                               // N*3, aliases ad+ni
    unsigned int* off_d = (unsigned int*)(ni + (size_t)N * 4);  // N+4
    unsigned int* off_s = off_d + (size_t)N + 4;       // N+4
    unsigned int* gh_d  = off_s + (size_t)N + 4;       // 1024
    unsigned int* gh_s  = gh_d + 1024;                 // 1024
    unsigned int* coff_d = gh_s + 1024;                // 1024
    unsigned int* coff_s = coff_d + 1024;              // 1024
    unsigned int* cur_d  = coff_s + 1024;              // 1024
    unsigned int* cur_s  = cur_d + 1024;               // 1024
    int* srcs = (int*)(cur_s + 1024);                  // Et
    int* dsts = srcs + (size_t)Et;                     // Et
    float2* w2 = (float2*)(dsts + (size_t)Et);         // Et float2
    unsigned short* Wb = (unsigned short*)(w2 + (size_t)Et);  // 3*16384 bf16

    // output layout (floats): x_embed | node_output | ypred | y_nodepred
    float* o_embed = (float*)d_out;
    float* o_node  = o_embed + (size_t)N * 128;
    float* o_ypred = o_node + (size_t)M * 3;
    float* o_ynode = o_ypred + (size_t)N;

    const int gemm_blocks = (N + 63) / 64;
    const int node_wave_blocks = (N + 3) / 4;
    const int n_blocks = (N + 255) / 256;

    // ---- 2-level CSR build (once) ----
    hipMemsetAsync(gh_d, 0, 2048 * sizeof(unsigned int), stream);
    coarse_hist<<<NBLK, 512, 0, stream>>>(ei, E, Et, gh_d, gh_s, CB);
    coarse_scan<<<1, 1024, 0, stream>>>(gh_d, gh_s, coff_d, coff_s, cur_d, cur_s,
                                        CB, (unsigned int)Et);
    coarse_scatter_both<<<NBLK, 512, 0, stream>>>(ei, E, Et, cur_d, cur_s, tmp_d, tmp_s, CB);
    fine_sort<<<2 * CB, 256, 0, stream>>>(tmp_d, tmp_s, coff_d, coff_s, off_d, off_s,
                                          srcs, dsts, N, CB, (unsigned int)Et);

    for (int L = 0; L < 3; ++L) {
        const float* hin = (L == 0) ? x : hb;
        wsplit<<<64, 256, 0, stream>>>(W[L], Wb);
        gemm_mfma<<<gemm_blocks, 256, 0, stream>>>(hin, Wb, att[L], xlin,
                                                   (float4*)ni, (float2*)ad, N);
        src_sum<<<n_blocks, 256, 0, stream>>>(dsts, off_s, (const float2*)ad, ni, N);
        edge_w<<<CB, 256, 0, stream>>>(srcs, off_d, (const float4*)ni, (const float2*)ad,
                                       w2, N);
        if (L < 2)
            agg_csr<false><<<node_wave_blocks, 256, 0, stream>>>(
                srcs, off_d, (const float2*)xlin, (const float2*)w2,
                b[L], hb, nullptr, nullptr, nullptr, nullptr, N);
        else
            agg_csr<true><<<node_wave_blocks, 256, 0, stream>>>(
                srcs, off_d, (const float2*)xlin, (const float2*)w2,
                b[L], o_embed, Wout, bout, out3, o_ypred, N);
    }
    gather_out<<<(M + 255) / 256, 256, 0, stream>>>(out3, o_ypred, node_index, o_node, o_ynode, M);
}

// Round 12
// 476.222 us; speedup vs baseline: 1.0294x; 1.0294x over previous
//
#include <hip/hip_runtime.h>
#include <math.h>

// ---------------------------------------------------------------------------
// GAT forward (3 layers) on MI355X. f32. N=50000, D=128, H=2, k=64.
// E=800000 real edges + N self-loops (Et=850000).
// Round 12: revert to the round-9 f32 pipeline (MFMA/bf16x3 abandoned: its
// ~2e-3 logit error straddles the min argmax margin -> coin-flip failures).
// Change: agg_csr processes 2 edges/wave (lane = float4 of 4 features,
// halves of the wave take alternate edges; cross-half shfl reduce at end).
// ---------------------------------------------------------------------------

#define EPB 8192   // edges per coarse block

// C = A(N x 128) @ W^T(128 x 128), f32. Epilogue computes the per-node
// attention dots from acc registers (a_dst -> ad2, a_src -> ni.xy).
__global__ __launch_bounds__(256) void gemm128(const float* __restrict__ A,
                                               const float* __restrict__ Wm,
                                               const float* __restrict__ att,
                                               float* __restrict__ C,
                                               float4* __restrict__ ni4,
                                               float2* __restrict__ ad2v, int N) {
    __shared__ float As[64][68];
    __shared__ float Wt[64][132];
    const int tx = threadIdx.x;
    const int row0 = blockIdx.x * 64;
    const int cid = tx & 31;
    const int rid = tx >> 5;
    float acc[8][4] = {};
    const float4* A4 = (const float4*)A;
    const float4* W4 = (const float4*)Wm;

    for (int kt = 0; kt < 2; ++kt) {
        for (int i = tx; i < 1024; i += 256) {
            int r = i >> 4, q = i & 15;
            int row = row0 + r;
            float4 v = (row < N) ? A4[(size_t)row * 32 + kt * 16 + q]
                                 : make_float4(0.f, 0.f, 0.f, 0.f);
            As[r][q * 4 + 0] = v.x; As[r][q * 4 + 1] = v.y;
            As[r][q * 4 + 2] = v.z; As[r][q * 4 + 3] = v.w;
        }
        for (int i = tx; i < 2048; i += 256) {
            int c = i >> 4, q = i & 15;
            float4 v = W4[(size_t)c * 32 + kt * 16 + q];
            Wt[q * 4 + 0][c] = v.x; Wt[q * 4 + 1][c] = v.y;
            Wt[q * 4 + 2][c] = v.z; Wt[q * 4 + 3][c] = v.w;
        }
        __syncthreads();
        for (int k = 0; k < 64; k += 4) {
            float4 a[8];
            #pragma unroll
            for (int i = 0; i < 8; ++i) a[i] = *(const float4*)&As[rid * 8 + i][k];
            #pragma unroll
            for (int kk = 0; kk < 4; ++kk) {
                float4 w = *(const float4*)&Wt[k + kk][cid * 4];
                #pragma unroll
                for (int i = 0; i < 8; ++i) {
                    float av = (kk == 0) ? a[i].x : (kk == 1) ? a[i].y : (kk == 2) ? a[i].z : a[i].w;
                    acc[i][0] += av * w.x; acc[i][1] += av * w.y;
                    acc[i][2] += av * w.z; acc[i][3] += av * w.w;
                }
            }
        }
        __syncthreads();
    }
    #pragma unroll
    for (int i = 0; i < 8; ++i) {
        int row = row0 + rid * 8 + i;
        if (row < N)
            ((float4*)C)[(size_t)row * 32 + cid] =
                make_float4(acc[i][0], acc[i][1], acc[i][2], acc[i][3]);
    }
    const int hh = cid >> 4;
    const int c0 = (cid & 15) * 4;
    float ad0 = att[hh * 128 + c0 + 0], ad1 = att[hh * 128 + c0 + 1];
    float ad2c = att[hh * 128 + c0 + 2], ad3 = att[hh * 128 + c0 + 3];
    float as0 = att[hh * 128 + 64 + c0 + 0], as1 = att[hh * 128 + 64 + c0 + 1];
    float as2 = att[hh * 128 + 64 + c0 + 2], as3 = att[hh * 128 + 64 + c0 + 3];
    float pd[8], ps[8];
    #pragma unroll
    for (int i = 0; i < 8; ++i) {
        pd[i] = acc[i][0] * ad0 + acc[i][1] * ad1 + acc[i][2] * ad2c + acc[i][3] * ad3;
        ps[i] = acc[i][0] * as0 + acc[i][1] * as1 + acc[i][2] * as2 + acc[i][3] * as3;
    }
    #pragma unroll
    for (int m = 1; m < 16; m <<= 1) {
        #pragma unroll
        for (int i = 0; i < 8; ++i) {
            pd[i] += __shfl_xor(pd[i], m);
            ps[i] += __shfl_xor(ps[i], m);
        }
    }
    const int ll = tx & 63;
    const int grp = ll & 32;
    #pragma unroll
    for (int i = 0; i < 8; ++i) {
        float d0 = __shfl(pd[i], grp + 0);
        float d1 = __shfl(pd[i], grp + 16);
        float s0 = __shfl(ps[i], grp + 0);
        float s1 = __shfl(ps[i], grp + 16);
        if ((ll & 31) == 0) {
            int row = row0 + rid * 8 + i;
            if (row < N) {
                ad2v[row] = make_float2(d0, d1);
                ni4[row] = make_float4(s0, s1, 0.f, 0.f);
            }
        }
    }
}

// ----------------------- 2-level CSR build (once) --------------------------
__global__ __launch_bounds__(512) void coarse_hist(const int* __restrict__ ei, int E, int Et,
                                                   unsigned int* __restrict__ gh_d,
                                                   unsigned int* __restrict__ gh_s, int CB) {
    __shared__ unsigned int lh_d[800];
    __shared__ unsigned int lh_s[800];
    const int t = threadIdx.x;
    for (int b = t; b < CB; b += 512) { lh_d[b] = 0u; lh_s[b] = 0u; }
    __syncthreads();
    const int i0 = blockIdx.x * EPB;
    for (int i = t; i < EPB; i += 512) {
        int e = i0 + i;
        if (e < Et) {
            int s, d;
            if (e < E) { s = ei[e]; d = ei[E + e]; } else { s = d = e - E; }
            atomicAdd(&lh_d[d >> 6], 1u);
            atomicAdd(&lh_s[s >> 6], 1u);
        }
    }
    __syncthreads();
    for (int b = t; b < CB; b += 512) {
        if (lh_d[b]) atomicAdd(&gh_d[b], lh_d[b]);
        if (lh_s[b]) atomicAdd(&gh_s[b], lh_s[b]);
    }
}

__global__ __launch_bounds__(1024) void coarse_scan(const unsigned int* __restrict__ gh_d,
                                                    const unsigned int* __restrict__ gh_s,
                                                    unsigned int* __restrict__ coff_d,
                                                    unsigned int* __restrict__ coff_s,
                                                    unsigned int* __restrict__ cur_d,
                                                    unsigned int* __restrict__ cur_s,
                                                    int CB, unsigned int total) {
    __shared__ unsigned int sh[1024];
    const int t = threadIdx.x;
    for (int a = 0; a < 2; ++a) {
        const unsigned int* gh = a ? gh_s : gh_d;
        unsigned int* coff = a ? coff_s : coff_d;
        unsigned int* cur  = a ? cur_s : cur_d;
        sh[t] = (t < CB) ? gh[t] : 0u;
        __syncthreads();
        #pragma unroll
        for (int d = 1; d < 1024; d <<= 1) {
            unsigned int u = (t >= d) ? sh[t - d] : 0u;
            __syncthreads();
            sh[t] += u;
            __syncthreads();
        }
        if (t < CB) {
            unsigned int ex = (t == 0) ? 0u : sh[t - 1];
            coff[t] = ex;
            cur[t] = ex;
        }
        if (t == 0) coff[CB] = total;
        __syncthreads();
    }
}

__global__ __launch_bounds__(512) void coarse_scatter_both(const int* __restrict__ ei,
                                                           int E, int Et,
                                                           unsigned int* __restrict__ cur_d,
                                                           unsigned int* __restrict__ cur_s,
                                                           unsigned int* __restrict__ tmp_d,
                                                           unsigned int* __restrict__ tmp_s,
                                                           int CB) {
    __shared__ unsigned int lh_d[800];
    __shared__ unsigned int lh_s[800];
    const int t = threadIdx.x;
    for (int b = t; b < CB; b += 512) { lh_d[b] = 0u; lh_s[b] = 0u; }
    __syncthreads();
    const int i0 = blockIdx.x * EPB;
    for (int i = t; i < EPB; i += 512) {
        int e = i0 + i;
        if (e < Et) {
            int s, d;
            if (e < E) { s = ei[e]; d = ei[E + e]; } else { s = d = e - E; }
            atomicAdd(&lh_d[d >> 6], 1u);
            atomicAdd(&lh_s[s >> 6], 1u);
        }
    }
    __syncthreads();
    for (int b = t; b < CB; b += 512) {
        unsigned int cd = lh_d[b], cs = lh_s[b];
        lh_d[b] = cd ? atomicAdd(&cur_d[b], cd) : 0u;
        lh_s[b] = cs ? atomicAdd(&cur_s[b], cs) : 0u;
    }
    __syncthreads();
    for (int i = t; i < EPB; i += 512) {
        int e = i0 + i;
        if (e < Et) {
            int s, d;
            if (e < E) { s = ei[e]; d = ei[E + e]; } else { s = d = e - E; }
            unsigned int pd = atomicAdd(&lh_d[d >> 6], 1u);
            tmp_d[pd] = ((unsigned int)(d & 63) << 16) | (unsigned int)s;
            unsigned int ps = atomicAdd(&lh_s[s >> 6], 1u);
            tmp_s[ps] = ((unsigned int)(s & 63) << 16) | (unsigned int)d;
        }
    }
}

__global__ __launch_bounds__(256) void fine_sort(const unsigned int* __restrict__ tmp_d,
                                                 const unsigned int* __restrict__ tmp_s,
                                                 const unsigned int* __restrict__ coff_d,
                                                 const unsigned int* __restrict__ coff_s,
                                                 unsigned int* __restrict__ off_d,
                                                 unsigned int* __restrict__ off_s,
                                                 int* __restrict__ srcs,
                                                 int* __restrict__ dsts,
                                                 int N, int CB, unsigned int total) {
    __shared__ unsigned int cnt[64];
    __shared__ unsigned int h[64];
    const bool isS = (int)blockIdx.x >= CB;
    const int b = isS ? (blockIdx.x - CB) : blockIdx.x;
    const unsigned int* tmp  = isS ? tmp_s : tmp_d;
    const unsigned int* coff = isS ? coff_s : coff_d;
    unsigned int* off = isS ? off_s : off_d;
    int* outv = isS ? dsts : srcs;
    const int node0 = b * 64;
    int nn = N - node0; if (nn > 64) nn = 64;
    const int t = threadIdx.x;
    const unsigned int cb0 = coff[b], cb1 = coff[b + 1];
    if (t < 64) cnt[t] = 0u;
    __syncthreads();
    for (unsigned int i = cb0 + t; i < cb1; i += 256)
        atomicAdd(&cnt[tmp[i] >> 16], 1u);
    __syncthreads();
    if (t < 64) h[t] = cnt[t];
    __syncthreads();
    #pragma unroll
    for (int d = 1; d < 64; d <<= 1) {
        unsigned int u = (t < 64 && t >= d) ? h[t - d] : 0u;
        __syncthreads();
        if (t < 64) h[t] += u;
        __syncthreads();
    }
    if (t < 64) h[t] = cb0 + h[t] - cnt[t];
    __syncthreads();
    if (t < nn) off[node0 + t] = h[t];
    if (b == CB - 1 && t == 0) off[N] = total;
    for (unsigned int i = cb0 + t; i < cb1; i += 256) {
        unsigned int v = tmp[i];
        unsigned int pos = atomicAdd(&h[v >> 16], 1u);
        outv[pos] = (int)(v & 0xFFFFu);
    }
}

// ---- softmax denominator per src node -------------------------------------
__global__ __launch_bounds__(256) void src_sum(const int* __restrict__ dsts,
                                               const unsigned int* __restrict__ off_s,
                                               const float2* __restrict__ ad2,
                                               float* __restrict__ ni, int N) {
    int n = blockIdx.x * 256 + threadIdx.x;
    if (n >= N) return;
    float as0 = ni[(size_t)n * 4 + 0];
    float as1 = ni[(size_t)n * 4 + 1];
    unsigned int j0 = off_s[n], j1 = off_s[n + 1];
    float s0 = 0.f, s1 = 0.f;
    unsigned int j = j0;
    for (; j + 4 <= j1; j += 4) {
        int d0 = dsts[j], d1 = dsts[j + 1], d2 = dsts[j + 2], d3 = dsts[j + 3];
        float2 a0 = ad2[d0], a1 = ad2[d1], a2 = ad2[d2], a3 = ad2[d3];
        float t;
        t = as0 + a0.x; t = (t > 0.f) ? t : 0.2f * t; s0 += __expf(t);
        t = as1 + a0.y; t = (t > 0.f) ? t : 0.2f * t; s1 += __expf(t);
        t = as0 + a1.x; t = (t > 0.f) ? t : 0.2f * t; s0 += __expf(t);
        t = as1 + a1.y; t = (t > 0.f) ? t : 0.2f * t; s1 += __expf(t);
        t = as0 + a2.x; t = (t > 0.f) ? t : 0.2f * t; s0 += __expf(t);
        t = as1 + a2.y; t = (t > 0.f) ? t : 0.2f * t; s1 += __expf(t);
        t = as0 + a3.x; t = (t > 0.f) ? t : 0.2f * t; s0 += __expf(t);
        t = as1 + a3.y; t = (t > 0.f) ? t : 0.2f * t; s1 += __expf(t);
    }
    for (; j < j1; ++j) {
        float2 a = ad2[dsts[j]];
        float t;
        t = as0 + a.x; t = (t > 0.f) ? t : 0.2f * t; s0 += __expf(t);
        t = as1 + a.y; t = (t > 0.f) ? t : 0.2f * t; s1 += __expf(t);
    }
    ni[(size_t)n * 4 + 2] = 1.0f / (s0 + 1e-16f);
    ni[(size_t)n * 4 + 3] = 1.0f / (s1 + 1e-16f);
}

// ---- per-edge weights in dst-CSR order ------------------------------------
__global__ __launch_bounds__(256) void edge_w(const int* __restrict__ srcs,
                                              const unsigned int* __restrict__ off_d,
                                              const float4* __restrict__ ni4,
                                              const float2* __restrict__ ad2,
                                              float2* __restrict__ w2, int N) {
    __shared__ unsigned int lb[65];
    __shared__ float2 lad[64];
    const int node0 = blockIdx.x * 64;
    int nn = N - node0; if (nn > 64) nn = 64;
    const int t = threadIdx.x;
    if (t <= nn) lb[t] = off_d[node0 + t];
    if (t < nn) lad[t] = ad2[node0 + t];
    __syncthreads();
    unsigned int base = lb[0], end = lb[nn];
    for (unsigned int i = base + t; i < end; i += 256) {
        int lo = 0, hi = nn;
        while (hi - lo > 1) {
            int mid = (lo + hi) >> 1;
            if (i >= lb[mid]) lo = mid; else hi = mid;
        }
        float2 ad = lad[lo];
        int s = srcs[i];
        float4 nv = ni4[s];
        float a0 = ad.x + nv.x; a0 = (a0 > 0.f) ? a0 : 0.2f * a0;
        float a1 = ad.y + nv.y; a1 = (a1 > 0.f) ? a1 : 0.2f * a1;
        w2[i] = make_float2(__expf(a0) * nv.z, __expf(a1) * nv.w);
    }
}

// ---------------- CSR aggregation: one wave per dst node -------------------
// lane = float4 of 4 features (fl = lane&31); wave halves take alternate
// edges; cross-half shfl_xor(.,32) reduce at the end.
template <int U>
__device__ __forceinline__ void agg_pairs(unsigned int j, const int* __restrict__ srcs,
                                          const float2* __restrict__ w2,
                                          const float4* __restrict__ x4,
                                          int fl, int half, float4& acc) {
    int s[U]; float2 w[U]; float4 v[U];
    #pragma unroll
    for (int u = 0; u < U; ++u) s[u] = srcs[j + 2 * u + half];
    #pragma unroll
    for (int u = 0; u < U; ++u) w[u] = w2[j + 2 * u + half];
    #pragma unroll
    for (int u = 0; u < U; ++u) v[u] = x4[(size_t)s[u] * 32 + fl];
    #pragma unroll
    for (int u = 0; u < U; ++u) {
        float ww = (fl < 16) ? w[u].x : w[u].y;
        acc.x += v[u].x * ww; acc.y += v[u].y * ww;
        acc.z += v[u].z * ww; acc.w += v[u].w * ww;
    }
}

template <bool LAST>
__global__ __launch_bounds__(256) void agg_csr(const int* __restrict__ srcs,
                                               const unsigned int* __restrict__ off,
                                               const float4* __restrict__ x4,
                                               const float2* __restrict__ w2,
                                               const float* __restrict__ bias,
                                               float* __restrict__ out,
                                               const float* __restrict__ Wout,
                                               const float* __restrict__ bout,
                                               float* __restrict__ out3,
                                               float* __restrict__ ypred, int N) {
    int d = blockIdx.x * 4 + (threadIdx.x >> 6);
    int l = threadIdx.x & 63;
    if (d >= N) return;
    d = __builtin_amdgcn_readfirstlane(d);
    const int fl = l & 31;      // float4 feature index
    const int half = l >> 5;    // which edge of the pair
    unsigned int j0 = off[d], j1 = off[d + 1];
    float4 acc = make_float4(0.f, 0.f, 0.f, 0.f);
    unsigned int j = j0;
    for (; j + 8 <= j1; j += 8) agg_pairs<4>(j, srcs, w2, x4, fl, half, acc);
    if (j + 4 <= j1) { agg_pairs<2>(j, srcs, w2, x4, fl, half, acc); j += 4; }
    if (j + 2 <= j1) { agg_pairs<1>(j, srcs, w2, x4, fl, half, acc); j += 2; }
    if (j < j1 && half == 0) {  // odd tail: half 0 only
        int s = srcs[j];
        float2 w = w2[j];
        float4 v = x4[(size_t)s * 32 + fl];
        float ww = (fl < 16) ? w.x : w.y;
        acc.x += v.x * ww; acc.y += v.y * ww;
        acc.z += v.z * ww; acc.w += v.w * ww;
    }
    // cross-half reduce: lane l and l^32 hold the same 4 features
    acc.x += __shfl_xor(acc.x, 32);
    acc.y += __shfl_xor(acc.y, 32);
    acc.z += __shfl_xor(acc.z, 32);
    acc.w += __shfl_xor(acc.w, 32);

    float4 bb = ((const float4*)bias)[fl];
    float4 o = make_float4(fmaxf(acc.x + bb.x, 0.f), fmaxf(acc.y + bb.y, 0.f),
                           fmaxf(acc.z + bb.z, 0.f), fmaxf(acc.w + bb.w, 0.f));
    if (half == 0) ((float4*)out)[(size_t)d * 32 + fl] = o;
    if (LAST) {
        const float4* W4 = (const float4*)Wout;
        float4 wa = W4[fl], wb = W4[32 + fl], wc = W4[64 + fl];
        float p0 = o.x * wa.x + o.y * wa.y + o.z * wa.z + o.w * wa.w;
        float p1 = o.x * wb.x + o.y * wb.y + o.z * wb.z + o.w * wb.w;
        float p2 = o.x * wc.x + o.y * wc.y + o.z * wc.z + o.w * wc.w;
        #pragma unroll
        for (int m = 1; m < 32; m <<= 1) {   // stays within the 32-lane half
            p0 += __shfl_xor(p0, m);
            p1 += __shfl_xor(p1, m);
            p2 += __shfl_xor(p2, m);
        }
        if (l == 0) {
            p0 += bout[0]; p1 += bout[1]; p2 += bout[2];
            out3[d * 3 + 0] = p0; out3[d * 3 + 1] = p1; out3[d * 3 + 2] = p2;
            int am = 0; float best = p0;
            if (p1 > best) { best = p1; am = 1; }
            if (p2 > best) { best = p2; am = 2; }
            ypred[d] = (float)am;
        }
    }
}

__global__ __launch_bounds__(256) void gather_out(const float* __restrict__ out3,
                                                  const float* __restrict__ ypred,
                                                  const int* __restrict__ node_index,
                                                  float* __restrict__ node_out,
                                                  float* __restrict__ y_nodepred, int M) {
    int i = blockIdx.x * 256 + threadIdx.x;
    if (i >= M) return;
    int idx = node_index[i];
    node_out[i * 3 + 0] = out3[idx * 3 + 0];
    node_out[i * 3 + 1] = out3[idx * 3 + 1];
    node_out[i * 3 + 2] = out3[idx * 3 + 2];
    y_nodepred[i] = ypred[idx];
}

extern "C" void kernel_launch(void* const* d_in, const int* in_sizes, int n_in,
                              void* d_out, int out_size, void* d_ws, size_t ws_size,
                              hipStream_t stream) {
    const float* x          = (const float*)d_in[0];
    const int*   ei         = (const int*)d_in[1];
    const int*   node_index = (const int*)d_in[3];
    const float* W[3]   = {(const float*)d_in[4], (const float*)d_in[7], (const float*)d_in[10]};
    const float* att[3] = {(const float*)d_in[5], (const float*)d_in[8], (const float*)d_in[11]};
    const float* b[3]   = {(const float*)d_in[6], (const float*)d_in[9], (const float*)d_in[12]};
    const float* Wout = (const float*)d_in[13];
    const float* bout = (const float*)d_in[14];

    const int N  = in_sizes[0] / 128;
    const int E  = in_sizes[1] / 2;
    const int Et = E + N;
    const int M  = in_sizes[3];
    const int CB = (N + 63) / 64;            // coarse buckets (782)
    const int NBLK = (Et + EPB - 1) / EPB;   // coarse blocks (104)

    // workspace layout (floats), ~66 MB.
    float* ws     = (float*)d_ws;
    float* xlin   = ws;                               // N*128
    unsigned int* tmp_d = (unsigned int*)ws;          // Et (build only)
    unsigned int* tmp_s = tmp_d + (size_t)Et;         // Et (build only)
    float* hb     = xlin + (size_t)N * 128;           // N*128
    float* ad     = hb + (size_t)N * 128;             // N*2  (a_dst)
    float* ni     = ad + (size_t)N * 2;               // N*4  {as0,as1,rcp0,rcp1}
    float* out3   = ad;                               // N*3, aliases ad+ni
    unsigned int* off_d = (unsigned int*)(ni + (size_t)N * 4);  // N+4
    unsigned int* off_s = off_d + (size_t)N + 4;       // N+4
    unsigned int* gh_d  = off_s + (size_t)N + 4;       // 1024
    unsigned int* gh_s  = gh_d + 1024;                 // 1024
    unsigned int* coff_d = gh_s + 1024;                // 1024
    unsigned int* coff_s = coff_d + 1024;              // 1024
    unsigned int* cur_d  = coff_s + 1024;              // 1024
    unsigned int* cur_s  = cur_d + 1024;               // 1024
    int* srcs = (int*)(cur_s + 1024);                  // Et
    int* dsts = srcs + (size_t)Et;                     // Et
    float2* w2 = (float2*)(dsts + (size_t)Et);         // Et float2

    // output layout (floats): x_embed | node_output | ypred | y_nodepred
    float* o_embed = (float*)d_out;
    float* o_node  = o_embed + (size_t)N * 128;
    float* o_ypred = o_node + (size_t)M * 3;
    float* o_ynode = o_ypred + (size_t)N;

    const int gemm_blocks = (N + 63) / 64;
    const int node_wave_blocks = (N + 3) / 4;
    const int n_blocks = (N + 255) / 256;

    // ---- 2-level CSR build (once) ----
    hipMemsetAsync(gh_d, 0, 2048 * sizeof(unsigned int), stream);
    coarse_hist<<<NBLK, 512, 0, stream>>>(ei, E, Et, gh_d, gh_s, CB);
    coarse_scan<<<1, 1024, 0, stream>>>(gh_d, gh_s, coff_d, coff_s, cur_d, cur_s,
                                        CB, (unsigned int)Et);
    coarse_scatter_both<<<NBLK, 512, 0, stream>>>(ei, E, Et, cur_d, cur_s, tmp_d, tmp_s, CB);
    fine_sort<<<2 * CB, 256, 0, stream>>>(tmp_d, tmp_s, coff_d, coff_s, off_d, off_s,
                                          srcs, dsts, N, CB, (unsigned int)Et);

    for (int L = 0; L < 3; ++L) {
        const float* hin = (L == 0) ? x : hb;
        gemm128<<<gemm_blocks, 256, 0, stream>>>(hin, W[L], att[L], xlin,
                                                 (float4*)ni, (float2*)ad, N);
        src_sum<<<n_blocks, 256, 0, stream>>>(dsts, off_s, (const float2*)ad, ni, N);
        edge_w<<<CB, 256, 0, stream>>>(srcs, off_d, (const float4*)ni, (const float2*)ad,
                                       w2, N);
        if (L < 2)
            agg_csr<false><<<node_wave_blocks, 256, 0, stream>>>(
                srcs, off_d, (const float4*)xlin, (const float2*)w2,
                b[L], hb, nullptr, nullptr, nullptr, nullptr, N);
        else
            agg_csr<true><<<node_wave_blocks, 256, 0, stream>>>(
                srcs, off_d, (const float4*)xlin, (const float2*)w2,
                b[L], o_embed, Wout, bout, out3, o_ypred, N);
    }
    gather_out<<<(M + 255) / 256, 256, 0, stream>>>(out3, o_ypred, node_index, o_node, o_ynode, M);
}

// Round 13
// 423.856 us; speedup vs baseline: 1.1566x; 1.1235x over previous
//
#include <hip/hip_runtime.h>
#include <math.h>

// ---------------------------------------------------------------------------
// GAT forward (3 layers) on MI355X. f32. N=50000, D=128, H=2, k=64.
// E=800000 real edges + N self-loops (Et=850000).
// Round 13: agg_csr reverted to round-9 exact form (pair-split regressed:
// ds_permute shuffles + half-wave coalescing). gemm128 tile doubled to
// 128 rows / 512 threads (W-staging amortized 2x, 4 waves/SIMD).
// ---------------------------------------------------------------------------

#define EPB 8192   // edges per coarse block

// C = A(N x 128) @ W^T(128 x 128), f32, 128-row tiles, 512 threads.
// Epilogue computes per-node attention dots from acc registers.
__global__ __launch_bounds__(512) void gemm128(const float* __restrict__ A,
                                               const float* __restrict__ Wm,
                                               const float* __restrict__ att,
                                               float* __restrict__ C,
                                               float4* __restrict__ ni4,
                                               float2* __restrict__ ad2v, int N) {
    __shared__ float As[128][68];
    __shared__ float Wt[64][132];
    const int tx = threadIdx.x;
    const int row0 = blockIdx.x * 128;
    const int cid = tx & 31;
    const int rid = tx >> 5;     // 16 row-groups of 8 rows
    float acc[8][4] = {};
    const float4* A4 = (const float4*)A;
    const float4* W4 = (const float4*)Wm;

    for (int kt = 0; kt < 2; ++kt) {
        for (int i = tx; i < 2048; i += 512) {   // 128 rows x 16 float4
            int r = i >> 4, q = i & 15;
            int row = row0 + r;
            float4 v = (row < N) ? A4[(size_t)row * 32 + kt * 16 + q]
                                 : make_float4(0.f, 0.f, 0.f, 0.f);
            As[r][q * 4 + 0] = v.x; As[r][q * 4 + 1] = v.y;
            As[r][q * 4 + 2] = v.z; As[r][q * 4 + 3] = v.w;
        }
        for (int i = tx; i < 2048; i += 512) {   // 128 cols x 16 float4 of k
            int c = i >> 4, q = i & 15;
            float4 v = W4[(size_t)c * 32 + kt * 16 + q];
            Wt[q * 4 + 0][c] = v.x; Wt[q * 4 + 1][c] = v.y;
            Wt[q * 4 + 2][c] = v.z; Wt[q * 4 + 3][c] = v.w;
        }
        __syncthreads();
        for (int k = 0; k < 64; k += 4) {
            float4 a[8];
            #pragma unroll
            for (int i = 0; i < 8; ++i) a[i] = *(const float4*)&As[rid * 8 + i][k];
            #pragma unroll
            for (int kk = 0; kk < 4; ++kk) {
                float4 w = *(const float4*)&Wt[k + kk][cid * 4];
                #pragma unroll
                for (int i = 0; i < 8; ++i) {
                    float av = (kk == 0) ? a[i].x : (kk == 1) ? a[i].y : (kk == 2) ? a[i].z : a[i].w;
                    acc[i][0] += av * w.x; acc[i][1] += av * w.y;
                    acc[i][2] += av * w.z; acc[i][3] += av * w.w;
                }
            }
        }
        __syncthreads();
    }
    #pragma unroll
    for (int i = 0; i < 8; ++i) {
        int row = row0 + rid * 8 + i;
        if (row < N)
            ((float4*)C)[(size_t)row * 32 + cid] =
                make_float4(acc[i][0], acc[i][1], acc[i][2], acc[i][3]);
    }
    const int hh = cid >> 4;
    const int c0 = (cid & 15) * 4;
    float ad0 = att[hh * 128 + c0 + 0], ad1 = att[hh * 128 + c0 + 1];
    float ad2c = att[hh * 128 + c0 + 2], ad3 = att[hh * 128 + c0 + 3];
    float as0 = att[hh * 128 + 64 + c0 + 0], as1 = att[hh * 128 + 64 + c0 + 1];
    float as2 = att[hh * 128 + 64 + c0 + 2], as3 = att[hh * 128 + 64 + c0 + 3];
    float pd[8], ps[8];
    #pragma unroll
    for (int i = 0; i < 8; ++i) {
        pd[i] = acc[i][0] * ad0 + acc[i][1] * ad1 + acc[i][2] * ad2c + acc[i][3] * ad3;
        ps[i] = acc[i][0] * as0 + acc[i][1] * as1 + acc[i][2] * as2 + acc[i][3] * as3;
    }
    #pragma unroll
    for (int m = 1; m < 16; m <<= 1) {
        #pragma unroll
        for (int i = 0; i < 8; ++i) {
            pd[i] += __shfl_xor(pd[i], m);
            ps[i] += __shfl_xor(ps[i], m);
        }
    }
    const int ll = tx & 63;
    const int grp = ll & 32;
    #pragma unroll
    for (int i = 0; i < 8; ++i) {
        float d0 = __shfl(pd[i], grp + 0);
        float d1 = __shfl(pd[i], grp + 16);
        float s0 = __shfl(ps[i], grp + 0);
        float s1 = __shfl(ps[i], grp + 16);
        if ((ll & 31) == 0) {
            int row = row0 + rid * 8 + i;
            if (row < N) {
                ad2v[row] = make_float2(d0, d1);
                ni4[row] = make_float4(s0, s1, 0.f, 0.f);
            }
        }
    }
}

// ----------------------- 2-level CSR build (once) --------------------------
__global__ __launch_bounds__(512) void coarse_hist(const int* __restrict__ ei, int E, int Et,
                                                   unsigned int* __restrict__ gh_d,
                                                   unsigned int* __restrict__ gh_s, int CB) {
    __shared__ unsigned int lh_d[800];
    __shared__ unsigned int lh_s[800];
    const int t = threadIdx.x;
    for (int b = t; b < CB; b += 512) { lh_d[b] = 0u; lh_s[b] = 0u; }
    __syncthreads();
    const int i0 = blockIdx.x * EPB;
    for (int i = t; i < EPB; i += 512) {
        int e = i0 + i;
        if (e < Et) {
            int s, d;
            if (e < E) { s = ei[e]; d = ei[E + e]; } else { s = d = e - E; }
            atomicAdd(&lh_d[d >> 6], 1u);
            atomicAdd(&lh_s[s >> 6], 1u);
        }
    }
    __syncthreads();
    for (int b = t; b < CB; b += 512) {
        if (lh_d[b]) atomicAdd(&gh_d[b], lh_d[b]);
        if (lh_s[b]) atomicAdd(&gh_s[b], lh_s[b]);
    }
}

__global__ __launch_bounds__(1024) void coarse_scan(const unsigned int* __restrict__ gh_d,
                                                    const unsigned int* __restrict__ gh_s,
                                                    unsigned int* __restrict__ coff_d,
                                                    unsigned int* __restrict__ coff_s,
                                                    unsigned int* __restrict__ cur_d,
                                                    unsigned int* __restrict__ cur_s,
                                                    int CB, unsigned int total) {
    __shared__ unsigned int sh[1024];
    const int t = threadIdx.x;
    for (int a = 0; a < 2; ++a) {
        const unsigned int* gh = a ? gh_s : gh_d;
        unsigned int* coff = a ? coff_s : coff_d;
        unsigned int* cur  = a ? cur_s : cur_d;
        sh[t] = (t < CB) ? gh[t] : 0u;
        __syncthreads();
        #pragma unroll
        for (int d = 1; d < 1024; d <<= 1) {
            unsigned int u = (t >= d) ? sh[t - d] : 0u;
            __syncthreads();
            sh[t] += u;
            __syncthreads();
        }
        if (t < CB) {
            unsigned int ex = (t == 0) ? 0u : sh[t - 1];
            coff[t] = ex;
            cur[t] = ex;
        }
        if (t == 0) coff[CB] = total;
        __syncthreads();
    }
}

__global__ __launch_bounds__(512) void coarse_scatter_both(const int* __restrict__ ei,
                                                           int E, int Et,
                                                           unsigned int* __restrict__ cur_d,
                                                           unsigned int* __restrict__ cur_s,
                                                           unsigned int* __restrict__ tmp_d,
                                                           unsigned int* __restrict__ tmp_s,
                                                           int CB) {
    __shared__ unsigned int lh_d[800];
    __shared__ unsigned int lh_s[800];
    const int t = threadIdx.x;
    for (int b = t; b < CB; b += 512) { lh_d[b] = 0u; lh_s[b] = 0u; }
    __syncthreads();
    const int i0 = blockIdx.x * EPB;
    for (int i = t; i < EPB; i += 512) {
        int e = i0 + i;
        if (e < Et) {
            int s, d;
            if (e < E) { s = ei[e]; d = ei[E + e]; } else { s = d = e - E; }
            atomicAdd(&lh_d[d >> 6], 1u);
            atomicAdd(&lh_s[s >> 6], 1u);
        }
    }
    __syncthreads();
    for (int b = t; b < CB; b += 512) {
        unsigned int cd = lh_d[b], cs = lh_s[b];
        lh_d[b] = cd ? atomicAdd(&cur_d[b], cd) : 0u;
        lh_s[b] = cs ? atomicAdd(&cur_s[b], cs) : 0u;
    }
    __syncthreads();
    for (int i = t; i < EPB; i += 512) {
        int e = i0 + i;
        if (e < Et) {
            int s, d;
            if (e < E) { s = ei[e]; d = ei[E + e]; } else { s = d = e - E; }
            unsigned int pd = atomicAdd(&lh_d[d >> 6], 1u);
            tmp_d[pd] = ((unsigned int)(d & 63) << 16) | (unsigned int)s;
            unsigned int ps = atomicAdd(&lh_s[s >> 6], 1u);
            tmp_s[ps] = ((unsigned int)(s & 63) << 16) | (unsigned int)d;
        }
    }
}

__global__ __launch_bounds__(256) void fine_sort(const unsigned int* __restrict__ tmp_d,
                                                 const unsigned int* __restrict__ tmp_s,
                                                 const unsigned int* __restrict__ coff_d,
                                                 const unsigned int* __restrict__ coff_s,
                                                 unsigned int* __restrict__ off_d,
                                                 unsigned int* __restrict__ off_s,
                                                 int* __restrict__ srcs,
                                                 int* __restrict__ dsts,
                                                 int N, int CB, unsigned int total) {
    __shared__ unsigned int cnt[64];
    __shared__ unsigned int h[64];
    const bool isS = (int)blockIdx.x >= CB;
    const int b = isS ? (blockIdx.x - CB) : blockIdx.x;
    const unsigned int* tmp  = isS ? tmp_s : tmp_d;
    const unsigned int* coff = isS ? coff_s : coff_d;
    unsigned int* off = isS ? off_s : off_d;
    int* outv = isS ? dsts : srcs;
    const int node0 = b * 64;
    int nn = N - node0; if (nn > 64) nn = 64;
    const int t = threadIdx.x;
    const unsigned int cb0 = coff[b], cb1 = coff[b + 1];
    if (t < 64) cnt[t] = 0u;
    __syncthreads();
    for (unsigned int i = cb0 + t; i < cb1; i += 256)
        atomicAdd(&cnt[tmp[i] >> 16], 1u);
    __syncthreads();
    if (t < 64) h[t] = cnt[t];
    __syncthreads();
    #pragma unroll
    for (int d = 1; d < 64; d <<= 1) {
        unsigned int u = (t < 64 && t >= d) ? h[t - d] : 0u;
        __syncthreads();
        if (t < 64) h[t] += u;
        __syncthreads();
    }
    if (t < 64) h[t] = cb0 + h[t] - cnt[t];
    __syncthreads();
    if (t < nn) off[node0 + t] = h[t];
    if (b == CB - 1 && t == 0) off[N] = total;
    for (unsigned int i = cb0 + t; i < cb1; i += 256) {
        unsigned int v = tmp[i];
        unsigned int pos = atomicAdd(&h[v >> 16], 1u);
        outv[pos] = (int)(v & 0xFFFFu);
    }
}

// ---- softmax denominator per src node -------------------------------------
__global__ __launch_bounds__(256) void src_sum(const int* __restrict__ dsts,
                                               const unsigned int* __restrict__ off_s,
                                               const float2* __restrict__ ad2,
                                               float* __restrict__ ni, int N) {
    int n = blockIdx.x * 256 + threadIdx.x;
    if (n >= N) return;
    float as0 = ni[(size_t)n * 4 + 0];
    float as1 = ni[(size_t)n * 4 + 1];
    unsigned int j0 = off_s[n], j1 = off_s[n + 1];
    float s0 = 0.f, s1 = 0.f;
    unsigned int j = j0;
    for (; j + 4 <= j1; j += 4) {
        int d0 = dsts[j], d1 = dsts[j + 1], d2 = dsts[j + 2], d3 = dsts[j + 3];
        float2 a0 = ad2[d0], a1 = ad2[d1], a2 = ad2[d2], a3 = ad2[d3];
        float t;
        t = as0 + a0.x; t = (t > 0.f) ? t : 0.2f * t; s0 += __expf(t);
        t = as1 + a0.y; t = (t > 0.f) ? t : 0.2f * t; s1 += __expf(t);
        t = as0 + a1.x; t = (t > 0.f) ? t : 0.2f * t; s0 += __expf(t);
        t = as1 + a1.y; t = (t > 0.f) ? t : 0.2f * t; s1 += __expf(t);
        t = as0 + a2.x; t = (t > 0.f) ? t : 0.2f * t; s0 += __expf(t);
        t = as1 + a2.y; t = (t > 0.f) ? t : 0.2f * t; s1 += __expf(t);
        t = as0 + a3.x; t = (t > 0.f) ? t : 0.2f * t; s0 += __expf(t);
        t = as1 + a3.y; t = (t > 0.f) ? t : 0.2f * t; s1 += __expf(t);
    }
    for (; j < j1; ++j) {
        float2 a = ad2[dsts[j]];
        float t;
        t = as0 + a.x; t = (t > 0.f) ? t : 0.2f * t; s0 += __expf(t);
        t = as1 + a.y; t = (t > 0.f) ? t : 0.2f * t; s1 += __expf(t);
    }
    ni[(size_t)n * 4 + 2] = 1.0f / (s0 + 1e-16f);
    ni[(size_t)n * 4 + 3] = 1.0f / (s1 + 1e-16f);
}

// ---- per-edge weights in dst-CSR order ------------------------------------
__global__ __launch_bounds__(256) void edge_w(const int* __restrict__ srcs,
                                              const unsigned int* __restrict__ off_d,
                                              const float4* __restrict__ ni4,
                                              const float2* __restrict__ ad2,
                                              float2* __restrict__ w2, int N) {
    __shared__ unsigned int lb[65];
    __shared__ float2 lad[64];
    const int node0 = blockIdx.x * 64;
    int nn = N - node0; if (nn > 64) nn = 64;
    const int t = threadIdx.x;
    if (t <= nn) lb[t] = off_d[node0 + t];
    if (t < nn) lad[t] = ad2[node0 + t];
    __syncthreads();
    unsigned int base = lb[0], end = lb[nn];
    for (unsigned int i = base + t; i < end; i += 256) {
        int lo = 0, hi = nn;
        while (hi - lo > 1) {
            int mid = (lo + hi) >> 1;
            if (i >= lb[mid]) lo = mid; else hi = mid;
        }
        float2 ad = lad[lo];
        int s = srcs[i];
        float4 nv = ni4[s];
        float a0 = ad.x + nv.x; a0 = (a0 > 0.f) ? a0 : 0.2f * a0;
        float a1 = ad.y + nv.y; a1 = (a1 > 0.f) ? a1 : 0.2f * a1;
        w2[i] = make_float2(__expf(a0) * nv.z, __expf(a1) * nv.w);
    }
}

// ---------------- CSR aggregation: one wave per dst node (round-9 form) ----
template <int U>
__device__ __forceinline__ void agg_edges(unsigned int j, const int* __restrict__ srcs,
                                          const float2* __restrict__ w2,
                                          const float2* __restrict__ x2,
                                          int l, int hi, float& accx, float& accy) {
    int s[U]; float2 w[U]; float2 v[U];
    #pragma unroll
    for (int u = 0; u < U; ++u) s[u] = srcs[j + u];
    #pragma unroll
    for (int u = 0; u < U; ++u) w[u] = w2[j + u];
    #pragma unroll
    for (int u = 0; u < U; ++u) v[u] = x2[(size_t)s[u] * 64 + l];
    #pragma unroll
    for (int u = 0; u < U; ++u) {
        float ww = hi ? w[u].y : w[u].x;
        accx += v[u].x * ww;
        accy += v[u].y * ww;
    }
}

template <bool LAST>
__global__ __launch_bounds__(256) void agg_csr(const int* __restrict__ srcs,
                                               const unsigned int* __restrict__ off,
                                               const float2* __restrict__ x2,
                                               const float2* __restrict__ w2,
                                               const float* __restrict__ bias,
                                               float* __restrict__ out,
                                               const float* __restrict__ Wout,
                                               const float* __restrict__ bout,
                                               float* __restrict__ out3,
                                               float* __restrict__ ypred, int N) {
    int d = blockIdx.x * 4 + (threadIdx.x >> 6);
    int l = threadIdx.x & 63;
    if (d >= N) return;
    d = __builtin_amdgcn_readfirstlane(d);
    const int hi = l >> 5;
    unsigned int j0 = off[d], j1 = off[d + 1];
    float accx = 0.f, accy = 0.f;
    unsigned int j = j0;
    for (; j + 16 <= j1; j += 16) agg_edges<16>(j, srcs, w2, x2, l, hi, accx, accy);
    if (j + 8 <= j1) { agg_edges<8>(j, srcs, w2, x2, l, hi, accx, accy); j += 8; }
    if (j + 4 <= j1) { agg_edges<4>(j, srcs, w2, x2, l, hi, accx, accy); j += 4; }
    if (j + 2 <= j1) { agg_edges<2>(j, srcs, w2, x2, l, hi, accx, accy); j += 2; }
    if (j < j1)      { agg_edges<1>(j, srcs, w2, x2, l, hi, accx, accy); }

    float2 bb = ((const float2*)bias)[l];
    float o0 = fmaxf(accx + bb.x, 0.f);
    float o1 = fmaxf(accy + bb.y, 0.f);
    ((float2*)out)[(size_t)d * 64 + l] = make_float2(o0, o1);
    if (LAST) {
        const float2* W2 = (const float2*)Wout;
        float2 wa = W2[l], wb = W2[64 + l], wc = W2[128 + l];
        float p0 = o0 * wa.x + o1 * wa.y;
        float p1 = o0 * wb.x + o1 * wb.y;
        float p2 = o0 * wc.x + o1 * wc.y;
        #pragma unroll
        for (int m = 32; m; m >>= 1) {
            p0 += __shfl_xor(p0, m);
            p1 += __shfl_xor(p1, m);
            p2 += __shfl_xor(p2, m);
        }
        if (l == 0) {
            p0 += bout[0]; p1 += bout[1]; p2 += bout[2];
            out3[d * 3 + 0] = p0; out3[d * 3 + 1] = p1; out3[d * 3 + 2] = p2;
            int am = 0; float best = p0;
            if (p1 > best) { best = p1; am = 1; }
            if (p2 > best) { best = p2; am = 2; }
            ypred[d] = (float)am;
        }
    }
}

__global__ __launch_bounds__(256) void gather_out(const float* __restrict__ out3,
                                                  const float* __restrict__ ypred,
                                                  const int* __restrict__ node_index,
                                                  float* __restrict__ node_out,
                                                  float* __restrict__ y_nodepred, int M) {
    int i = blockIdx.x * 256 + threadIdx.x;
    if (i >= M) return;
    int idx = node_index[i];
    node_out[i * 3 + 0] = out3[idx * 3 + 0];
    node_out[i * 3 + 1] = out3[idx * 3 + 1];
    node_out[i * 3 + 2] = out3[idx * 3 + 2];
    y_nodepred[i] = ypred[idx];
}

extern "C" void kernel_launch(void* const* d_in, const int* in_sizes, int n_in,
                              void* d_out, int out_size, void* d_ws, size_t ws_size,
                              hipStream_t stream) {
    const float* x          = (const float*)d_in[0];
    const int*   ei         = (const int*)d_in[1];
    const int*   node_index = (const int*)d_in[3];
    const float* W[3]   = {(const float*)d_in[4], (const float*)d_in[7], (const float*)d_in[10]};
    const float* att[3] = {(const float*)d_in[5], (const float*)d_in[8], (const float*)d_in[11]};
    const float* b[3]   = {(const float*)d_in[6], (const float*)d_in[9], (const float*)d_in[12]};
    const float* Wout = (const float*)d_in[13];
    const float* bout = (const float*)d_in[14];

    const int N  = in_sizes[0] / 128;
    const int E  = in_sizes[1] / 2;
    const int Et = E + N;
    const int M  = in_sizes[3];
    const int CB = (N + 63) / 64;            // coarse buckets (782)
    const int NBLK = (Et + EPB - 1) / EPB;   // coarse blocks (104)

    // workspace layout (floats), ~66 MB.
    float* ws     = (float*)d_ws;
    float* xlin   = ws;                               // N*128
    unsigned int* tmp_d = (unsigned int*)ws;          // Et (build only)
    unsigned int* tmp_s = tmp_d + (size_t)Et;         // Et (build only)
    float* hb     = xlin + (size_t)N * 128;           // N*128
    float* ad     = hb + (size_t)N * 128;             // N*2  (a_dst)
    float* ni     = ad + (size_t)N * 2;               // N*4  {as0,as1,rcp0,rcp1}
    float* out3   = ad;                               // N*3, aliases ad+ni
    unsigned int* off_d = (unsigned int*)(ni + (size_t)N * 4);  // N+4
    unsigned int* off_s = off_d + (size_t)N + 4;       // N+4
    unsigned int* gh_d  = off_s + (size_t)N + 4;       // 1024
    unsigned int* gh_s  = gh_d + 1024;                 // 1024
    unsigned int* coff_d = gh_s + 1024;                // 1024
    unsigned int* coff_s = coff_d + 1024;              // 1024
    unsigned int* cur_d  = coff_s + 1024;              // 1024
    unsigned int* cur_s  = cur_d + 1024;               // 1024
    int* srcs = (int*)(cur_s + 1024);                  // Et
    int* dsts = srcs + (size_t)Et;                     // Et
    float2* w2 = (float2*)(dsts + (size_t)Et);         // Et float2

    // output layout (floats): x_embed | node_output | ypred | y_nodepred
    float* o_embed = (float*)d_out;
    float* o_node  = o_embed + (size_t)N * 128;
    float* o_ypred = o_node + (size_t)M * 3;
    float* o_ynode = o_ypred + (size_t)N;

    const int gemm_blocks = (N + 127) / 128;
    const int node_wave_blocks = (N + 3) / 4;
    const int n_blocks = (N + 255) / 256;

    // ---- 2-level CSR build (once) ----
    hipMemsetAsync(gh_d, 0, 2048 * sizeof(unsigned int), stream);
    coarse_hist<<<NBLK, 512, 0, stream>>>(ei, E, Et, gh_d, gh_s, CB);
    coarse_scan<<<1, 1024, 0, stream>>>(gh_d, gh_s, coff_d, coff_s, cur_d, cur_s,
                                        CB, (unsigned int)Et);
    coarse_scatter_both<<<NBLK, 512, 0, stream>>>(ei, E, Et, cur_d, cur_s, tmp_d, tmp_s, CB);
    fine_sort<<<2 * CB, 256, 0, stream>>>(tmp_d, tmp_s, coff_d, coff_s, off_d, off_s,
                                          srcs, dsts, N, CB, (unsigned int)Et);

    for (int L = 0; L < 3; ++L) {
        const float* hin = (L == 0) ? x : hb;
        gemm128<<<gemm_blocks, 512, 0, stream>>>(hin, W[L], att[L], xlin,
                                                 (float4*)ni, (float2*)ad, N);
        src_sum<<<n_blocks, 256, 0, stream>>>(dsts, off_s, (const float2*)ad, ni, N);
        edge_w<<<CB, 256, 0, stream>>>(srcs, off_d, (const float4*)ni, (const float2*)ad,
                                       w2, N);
        if (L < 2)
            agg_csr<false><<<node_wave_blocks, 256, 0, stream>>>(
                srcs, off_d, (const float2*)xlin, (const float2*)w2,
                b[L], hb, nullptr, nullptr, nullptr, nullptr, N);
        else
            agg_csr<true><<<node_wave_blocks, 256, 0, stream>>>(
                srcs, off_d, (const float2*)xlin, (const float2*)w2,
                b[L], o_embed, Wout, bout, out3, o_ypred, N);
    }
    gather_out<<<(M + 255) / 256, 256, 0, stream>>>(out3, o_ypred, node_index, o_node, o_ynode, M);
}

// Round 14
// 423.466 us; speedup vs baseline: 1.1576x; 1.0009x over previous
//
#include <hip/hip_runtime.h>
#include <math.h>

// ---------------------------------------------------------------------------
// GAT forward (3 layers) on MI355X. f32. N=50000, D=128, H=2, k=64.
// E=800000 real edges + N self-loops (Et=850000).
// Round 14: consolidate on round-9 config (measured best, 419.3us):
// 64-row gemm + round-9 agg_csr. Single change: agg_csr runs 512 threads
// (8 waves = 8 dst nodes per block), per-wave code identical.
// ---------------------------------------------------------------------------

#define EPB 8192   // edges per coarse block

// C = A(N x 128) @ W^T(128 x 128), f32. Epilogue computes the per-node
// attention dots from acc registers (a_dst -> ad2, a_src -> ni.xy).
__global__ __launch_bounds__(256) void gemm128(const float* __restrict__ A,
                                               const float* __restrict__ Wm,
                                               const float* __restrict__ att,
                                               float* __restrict__ C,
                                               float4* __restrict__ ni4,
                                               float2* __restrict__ ad2v, int N) {
    __shared__ float As[64][68];
    __shared__ float Wt[64][132];
    const int tx = threadIdx.x;
    const int row0 = blockIdx.x * 64;
    const int cid = tx & 31;
    const int rid = tx >> 5;
    float acc[8][4] = {};
    const float4* A4 = (const float4*)A;
    const float4* W4 = (const float4*)Wm;

    for (int kt = 0; kt < 2; ++kt) {
        for (int i = tx; i < 1024; i += 256) {
            int r = i >> 4, q = i & 15;
            int row = row0 + r;
            float4 v = (row < N) ? A4[(size_t)row * 32 + kt * 16 + q]
                                 : make_float4(0.f, 0.f, 0.f, 0.f);
            As[r][q * 4 + 0] = v.x; As[r][q * 4 + 1] = v.y;
            As[r][q * 4 + 2] = v.z; As[r][q * 4 + 3] = v.w;
        }
        for (int i = tx; i < 2048; i += 256) {
            int c = i >> 4, q = i & 15;
            float4 v = W4[(size_t)c * 32 + kt * 16 + q];
            Wt[q * 4 + 0][c] = v.x; Wt[q * 4 + 1][c] = v.y;
            Wt[q * 4 + 2][c] = v.z; Wt[q * 4 + 3][c] = v.w;
        }
        __syncthreads();
        for (int k = 0; k < 64; k += 4) {
            float4 a[8];
            #pragma unroll
            for (int i = 0; i < 8; ++i) a[i] = *(const float4*)&As[rid * 8 + i][k];
            #pragma unroll
            for (int kk = 0; kk < 4; ++kk) {
                float4 w = *(const float4*)&Wt[k + kk][cid * 4];
                #pragma unroll
                for (int i = 0; i < 8; ++i) {
                    float av = (kk == 0) ? a[i].x : (kk == 1) ? a[i].y : (kk == 2) ? a[i].z : a[i].w;
                    acc[i][0] += av * w.x; acc[i][1] += av * w.y;
                    acc[i][2] += av * w.z; acc[i][3] += av * w.w;
                }
            }
        }
        __syncthreads();
    }
    #pragma unroll
    for (int i = 0; i < 8; ++i) {
        int row = row0 + rid * 8 + i;
        if (row < N)
            ((float4*)C)[(size_t)row * 32 + cid] =
                make_float4(acc[i][0], acc[i][1], acc[i][2], acc[i][3]);
    }
    const int hh = cid >> 4;
    const int c0 = (cid & 15) * 4;
    float ad0 = att[hh * 128 + c0 + 0], ad1 = att[hh * 128 + c0 + 1];
    float ad2c = att[hh * 128 + c0 + 2], ad3 = att[hh * 128 + c0 + 3];
    float as0 = att[hh * 128 + 64 + c0 + 0], as1 = att[hh * 128 + 64 + c0 + 1];
    float as2 = att[hh * 128 + 64 + c0 + 2], as3 = att[hh * 128 + 64 + c0 + 3];
    float pd[8], ps[8];
    #pragma unroll
    for (int i = 0; i < 8; ++i) {
        pd[i] = acc[i][0] * ad0 + acc[i][1] * ad1 + acc[i][2] * ad2c + acc[i][3] * ad3;
        ps[i] = acc[i][0] * as0 + acc[i][1] * as1 + acc[i][2] * as2 + acc[i][3] * as3;
    }
    #pragma unroll
    for (int m = 1; m < 16; m <<= 1) {
        #pragma unroll
        for (int i = 0; i < 8; ++i) {
            pd[i] += __shfl_xor(pd[i], m);
            ps[i] += __shfl_xor(ps[i], m);
        }
    }
    const int ll = tx & 63;
    const int grp = ll & 32;
    #pragma unroll
    for (int i = 0; i < 8; ++i) {
        float d0 = __shfl(pd[i], grp + 0);
        float d1 = __shfl(pd[i], grp + 16);
        float s0 = __shfl(ps[i], grp + 0);
        float s1 = __shfl(ps[i], grp + 16);
        if ((ll & 31) == 0) {
            int row = row0 + rid * 8 + i;
            if (row < N) {
                ad2v[row] = make_float2(d0, d1);
                ni4[row] = make_float4(s0, s1, 0.f, 0.f);
            }
        }
    }
}

// ----------------------- 2-level CSR build (once) --------------------------
__global__ __launch_bounds__(512) void coarse_hist(const int* __restrict__ ei, int E, int Et,
                                                   unsigned int* __restrict__ gh_d,
                                                   unsigned int* __restrict__ gh_s, int CB) {
    __shared__ unsigned int lh_d[800];
    __shared__ unsigned int lh_s[800];
    const int t = threadIdx.x;
    for (int b = t; b < CB; b += 512) { lh_d[b] = 0u; lh_s[b] = 0u; }
    __syncthreads();
    const int i0 = blockIdx.x * EPB;
    for (int i = t; i < EPB; i += 512) {
        int e = i0 + i;
        if (e < Et) {
            int s, d;
            if (e < E) { s = ei[e]; d = ei[E + e]; } else { s = d = e - E; }
            atomicAdd(&lh_d[d >> 6], 1u);
            atomicAdd(&lh_s[s >> 6], 1u);
        }
    }
    __syncthreads();
    for (int b = t; b < CB; b += 512) {
        if (lh_d[b]) atomicAdd(&gh_d[b], lh_d[b]);
        if (lh_s[b]) atomicAdd(&gh_s[b], lh_s[b]);
    }
}

__global__ __launch_bounds__(1024) void coarse_scan(const unsigned int* __restrict__ gh_d,
                                                    const unsigned int* __restrict__ gh_s,
                                                    unsigned int* __restrict__ coff_d,
                                                    unsigned int* __restrict__ coff_s,
                                                    unsigned int* __restrict__ cur_d,
                                                    unsigned int* __restrict__ cur_s,
                                                    int CB, unsigned int total) {
    __shared__ unsigned int sh[1024];
    const int t = threadIdx.x;
    for (int a = 0; a < 2; ++a) {
        const unsigned int* gh = a ? gh_s : gh_d;
        unsigned int* coff = a ? coff_s : coff_d;
        unsigned int* cur  = a ? cur_s : cur_d;
        sh[t] = (t < CB) ? gh[t] : 0u;
        __syncthreads();
        #pragma unroll
        for (int d = 1; d < 1024; d <<= 1) {
            unsigned int u = (t >= d) ? sh[t - d] : 0u;
            __syncthreads();
            sh[t] += u;
            __syncthreads();
        }
        if (t < CB) {
            unsigned int ex = (t == 0) ? 0u : sh[t - 1];
            coff[t] = ex;
            cur[t] = ex;
        }
        if (t == 0) coff[CB] = total;
        __syncthreads();
    }
}

__global__ __launch_bounds__(512) void coarse_scatter_both(const int* __restrict__ ei,
                                                           int E, int Et,
                                                           unsigned int* __restrict__ cur_d,
                                                           unsigned int* __restrict__ cur_s,
                                                           unsigned int* __restrict__ tmp_d,
                                                           unsigned int* __restrict__ tmp_s,
                                                           int CB) {
    __shared__ unsigned int lh_d[800];
    __shared__ unsigned int lh_s[800];
    const int t = threadIdx.x;
    for (int b = t; b < CB; b += 512) { lh_d[b] = 0u; lh_s[b] = 0u; }
    __syncthreads();
    const int i0 = blockIdx.x * EPB;
    for (int i = t; i < EPB; i += 512) {
        int e = i0 + i;
        if (e < Et) {
            int s, d;
            if (e < E) { s = ei[e]; d = ei[E + e]; } else { s = d = e - E; }
            atomicAdd(&lh_d[d >> 6], 1u);
            atomicAdd(&lh_s[s >> 6], 1u);
        }
    }
    __syncthreads();
    for (int b = t; b < CB; b += 512) {
        unsigned int cd = lh_d[b], cs = lh_s[b];
        lh_d[b] = cd ? atomicAdd(&cur_d[b], cd) : 0u;
        lh_s[b] = cs ? atomicAdd(&cur_s[b], cs) : 0u;
    }
    __syncthreads();
    for (int i = t; i < EPB; i += 512) {
        int e = i0 + i;
        if (e < Et) {
            int s, d;
            if (e < E) { s = ei[e]; d = ei[E + e]; } else { s = d = e - E; }
            unsigned int pd = atomicAdd(&lh_d[d >> 6], 1u);
            tmp_d[pd] = ((unsigned int)(d & 63) << 16) | (unsigned int)s;
            unsigned int ps = atomicAdd(&lh_s[s >> 6], 1u);
            tmp_s[ps] = ((unsigned int)(s & 63) << 16) | (unsigned int)d;
        }
    }
}

__global__ __launch_bounds__(256) void fine_sort(const unsigned int* __restrict__ tmp_d,
                                                 const unsigned int* __restrict__ tmp_s,
                                                 const unsigned int* __restrict__ coff_d,
                                                 const unsigned int* __restrict__ coff_s,
                                                 unsigned int* __restrict__ off_d,
                                                 unsigned int* __restrict__ off_s,
                                                 int* __restrict__ srcs,
                                                 int* __restrict__ dsts,
                                                 int N, int CB, unsigned int total) {
    __shared__ unsigned int cnt[64];
    __shared__ unsigned int h[64];
    const bool isS = (int)blockIdx.x >= CB;
    const int b = isS ? (blockIdx.x - CB) : blockIdx.x;
    const unsigned int* tmp  = isS ? tmp_s : tmp_d;
    const unsigned int* coff = isS ? coff_s : coff_d;
    unsigned int* off = isS ? off_s : off_d;
    int* outv = isS ? dsts : srcs;
    const int node0 = b * 64;
    int nn = N - node0; if (nn > 64) nn = 64;
    const int t = threadIdx.x;
    const unsigned int cb0 = coff[b], cb1 = coff[b + 1];
    if (t < 64) cnt[t] = 0u;
    __syncthreads();
    for (unsigned int i = cb0 + t; i < cb1; i += 256)
        atomicAdd(&cnt[tmp[i] >> 16], 1u);
    __syncthreads();
    if (t < 64) h[t] = cnt[t];
    __syncthreads();
    #pragma unroll
    for (int d = 1; d < 64; d <<= 1) {
        unsigned int u = (t < 64 && t >= d) ? h[t - d] : 0u;
        __syncthreads();
        if (t < 64) h[t] += u;
        __syncthreads();
    }
    if (t < 64) h[t] = cb0 + h[t] - cnt[t];
    __syncthreads();
    if (t < nn) off[node0 + t] = h[t];
    if (b == CB - 1 && t == 0) off[N] = total;
    for (unsigned int i = cb0 + t; i < cb1; i += 256) {
        unsigned int v = tmp[i];
        unsigned int pos = atomicAdd(&h[v >> 16], 1u);
        outv[pos] = (int)(v & 0xFFFFu);
    }
}

// ---- softmax denominator per src node -------------------------------------
__global__ __launch_bounds__(256) void src_sum(const int* __restrict__ dsts,
                                               const unsigned int* __restrict__ off_s,
                                               const float2* __restrict__ ad2,
                                               float* __restrict__ ni, int N) {
    int n = blockIdx.x * 256 + threadIdx.x;
    if (n >= N) return;
    float as0 = ni[(size_t)n * 4 + 0];
    float as1 = ni[(size_t)n * 4 + 1];
    unsigned int j0 = off_s[n], j1 = off_s[n + 1];
    float s0 = 0.f, s1 = 0.f;
    unsigned int j = j0;
    for (; j + 4 <= j1; j += 4) {
        int d0 = dsts[j], d1 = dsts[j + 1], d2 = dsts[j + 2], d3 = dsts[j + 3];
        float2 a0 = ad2[d0], a1 = ad2[d1], a2 = ad2[d2], a3 = ad2[d3];
        float t;
        t = as0 + a0.x; t = (t > 0.f) ? t : 0.2f * t; s0 += __expf(t);
        t = as1 + a0.y; t = (t > 0.f) ? t : 0.2f * t; s1 += __expf(t);
        t = as0 + a1.x; t = (t > 0.f) ? t : 0.2f * t; s0 += __expf(t);
        t = as1 + a1.y; t = (t > 0.f) ? t : 0.2f * t; s1 += __expf(t);
        t = as0 + a2.x; t = (t > 0.f) ? t : 0.2f * t; s0 += __expf(t);
        t = as1 + a2.y; t = (t > 0.f) ? t : 0.2f * t; s1 += __expf(t);
        t = as0 + a3.x; t = (t > 0.f) ? t : 0.2f * t; s0 += __expf(t);
        t = as1 + a3.y; t = (t > 0.f) ? t : 0.2f * t; s1 += __expf(t);
    }
    for (; j < j1; ++j) {
        float2 a = ad2[dsts[j]];
        float t;
        t = as0 + a.x; t = (t > 0.f) ? t : 0.2f * t; s0 += __expf(t);
        t = as1 + a.y; t = (t > 0.f) ? t : 0.2f * t; s1 += __expf(t);
    }
    ni[(size_t)n * 4 + 2] = 1.0f / (s0 + 1e-16f);
    ni[(size_t)n * 4 + 3] = 1.0f / (s1 + 1e-16f);
}

// ---- per-edge weights in dst-CSR order ------------------------------------
__global__ __launch_bounds__(256) void edge_w(const int* __restrict__ srcs,
                                              const unsigned int* __restrict__ off_d,
                                              const float4* __restrict__ ni4,
                                              const float2* __restrict__ ad2,
                                              float2* __restrict__ w2, int N) {
    __shared__ unsigned int lb[65];
    __shared__ float2 lad[64];
    const int node0 = blockIdx.x * 64;
    int nn = N - node0; if (nn > 64) nn = 64;
    const int t = threadIdx.x;
    if (t <= nn) lb[t] = off_d[node0 + t];
    if (t < nn) lad[t] = ad2[node0 + t];
    __syncthreads();
    unsigned int base = lb[0], end = lb[nn];
    for (unsigned int i = base + t; i < end; i += 256) {
        int lo = 0, hi = nn;
        while (hi - lo > 1) {
            int mid = (lo + hi) >> 1;
            if (i >= lb[mid]) lo = mid; else hi = mid;
        }
        float2 ad = lad[lo];
        int s = srcs[i];
        float4 nv = ni4[s];
        float a0 = ad.x + nv.x; a0 = (a0 > 0.f) ? a0 : 0.2f * a0;
        float a1 = ad.y + nv.y; a1 = (a1 > 0.f) ? a1 : 0.2f * a1;
        w2[i] = make_float2(__expf(a0) * nv.z, __expf(a1) * nv.w);
    }
}

// ---------------- CSR aggregation: one wave per dst node -------------------
template <int U>
__device__ __forceinline__ void agg_edges(unsigned int j, const int* __restrict__ srcs,
                                          const float2* __restrict__ w2,
                                          const float2* __restrict__ x2,
                                          int l, int hi, float& accx, float& accy) {
    int s[U]; float2 w[U]; float2 v[U];
    #pragma unroll
    for (int u = 0; u < U; ++u) s[u] = srcs[j + u];
    #pragma unroll
    for (int u = 0; u < U; ++u) w[u] = w2[j + u];
    #pragma unroll
    for (int u = 0; u < U; ++u) v[u] = x2[(size_t)s[u] * 64 + l];
    #pragma unroll
    for (int u = 0; u < U; ++u) {
        float ww = hi ? w[u].y : w[u].x;
        accx += v[u].x * ww;
        accy += v[u].y * ww;
    }
}

template <bool LAST>
__global__ __launch_bounds__(512) void agg_csr(const int* __restrict__ srcs,
                                               const unsigned int* __restrict__ off,
                                               const float2* __restrict__ x2,
                                               const float2* __restrict__ w2,
                                               const float* __restrict__ bias,
                                               float* __restrict__ out,
                                               const float* __restrict__ Wout,
                                               const float* __restrict__ bout,
                                               float* __restrict__ out3,
                                               float* __restrict__ ypred, int N) {
    int d = blockIdx.x * 8 + (threadIdx.x >> 6);
    int l = threadIdx.x & 63;
    if (d >= N) return;
    d = __builtin_amdgcn_readfirstlane(d);
    const int hi = l >> 5;
    unsigned int j0 = off[d], j1 = off[d + 1];
    float accx = 0.f, accy = 0.f;
    unsigned int j = j0;
    for (; j + 16 <= j1; j += 16) agg_edges<16>(j, srcs, w2, x2, l, hi, accx, accy);
    if (j + 8 <= j1) { agg_edges<8>(j, srcs, w2, x2, l, hi, accx, accy); j += 8; }
    if (j + 4 <= j1) { agg_edges<4>(j, srcs, w2, x2, l, hi, accx, accy); j += 4; }
    if (j + 2 <= j1) { agg_edges<2>(j, srcs, w2, x2, l, hi, accx, accy); j += 2; }
    if (j < j1)      { agg_edges<1>(j, srcs, w2, x2, l, hi, accx, accy); }

    float2 bb = ((const float2*)bias)[l];
    float o0 = fmaxf(accx + bb.x, 0.f);
    float o1 = fmaxf(accy + bb.y, 0.f);
    ((float2*)out)[(size_t)d * 64 + l] = make_float2(o0, o1);
    if (LAST) {
        const float2* W2 = (const float2*)Wout;
        float2 wa = W2[l], wb = W2[64 + l], wc = W2[128 + l];
        float p0 = o0 * wa.x + o1 * wa.y;
        float p1 = o0 * wb.x + o1 * wb.y;
        float p2 = o0 * wc.x + o1 * wc.y;
        #pragma unroll
        for (int m = 32; m; m >>= 1) {
            p0 += __shfl_xor(p0, m);
            p1 += __shfl_xor(p1, m);
            p2 += __shfl_xor(p2, m);
        }
        if (l == 0) {
            p0 += bout[0]; p1 += bout[1]; p2 += bout[2];
            out3[d * 3 + 0] = p0; out3[d * 3 + 1] = p1; out3[d * 3 + 2] = p2;
            int am = 0; float best = p0;
            if (p1 > best) { best = p1; am = 1; }
            if (p2 > best) { best = p2; am = 2; }
            ypred[d] = (float)am;
        }
    }
}

__global__ __launch_bounds__(256) void gather_out(const float* __restrict__ out3,
                                                  const float* __restrict__ ypred,
                                                  const int* __restrict__ node_index,
                                                  float* __restrict__ node_out,
                                                  float* __restrict__ y_nodepred, int M) {
    int i = blockIdx.x * 256 + threadIdx.x;
    if (i >= M) return;
    int idx = node_index[i];
    node_out[i * 3 + 0] = out3[idx * 3 + 0];
    node_out[i * 3 + 1] = out3[idx * 3 + 1];
    node_out[i * 3 + 2] = out3[idx * 3 + 2];
    y_nodepred[i] = ypred[idx];
}

extern "C" void kernel_launch(void* const* d_in, const int* in_sizes, int n_in,
                              void* d_out, int out_size, void* d_ws, size_t ws_size,
                              hipStream_t stream) {
    const float* x          = (const float*)d_in[0];
    const int*   ei         = (const int*)d_in[1];
    const int*   node_index = (const int*)d_in[3];
    const float* W[3]   = {(const float*)d_in[4], (const float*)d_in[7], (const float*)d_in[10]};
    const float* att[3] = {(const float*)d_in[5], (const float*)d_in[8], (const float*)d_in[11]};
    const float* b[3]   = {(const float*)d_in[6], (const float*)d_in[9], (const float*)d_in[12]};
    const float* Wout = (const float*)d_in[13];
    const float* bout = (const float*)d_in[14];

    const int N  = in_sizes[0] / 128;
    const int E  = in_sizes[1] / 2;
    const int Et = E + N;
    const int M  = in_sizes[3];
    const int CB = (N + 63) / 64;            // coarse buckets (782)
    const int NBLK = (Et + EPB - 1) / EPB;   // coarse blocks (104)

    // workspace layout (floats), ~66 MB.
    float* ws     = (float*)d_ws;
    float* xlin   = ws;                               // N*128
    unsigned int* tmp_d = (unsigned int*)ws;          // Et (build only)
    unsigned int* tmp_s = tmp_d + (size_t)Et;         // Et (build only)
    float* hb     = xlin + (size_t)N * 128;           // N*128
    float* ad     = hb + (size_t)N * 128;             // N*2  (a_dst)
    float* ni     = ad + (size_t)N * 2;               // N*4  {as0,as1,rcp0,rcp1}
    float* out3   = ad;                               // N*3, aliases ad+ni
    unsigned int* off_d = (unsigned int*)(ni + (size_t)N * 4);  // N+4
    unsigned int* off_s = off_d + (size_t)N + 4;       // N+4
    unsigned int* gh_d  = off_s + (size_t)N + 4;       // 1024
    unsigned int* gh_s  = gh_d + 1024;                 // 1024
    unsigned int* coff_d = gh_s + 1024;                // 1024
    unsigned int* coff_s = coff_d + 1024;              // 1024
    unsigned int* cur_d  = coff_s + 1024;              // 1024
    unsigned int* cur_s  = cur_d + 1024;               // 1024
    int* srcs = (int*)(cur_s + 1024);                  // Et
    int* dsts = srcs + (size_t)Et;                     // Et
    float2* w2 = (float2*)(dsts + (size_t)Et);         // Et float2

    // output layout (floats): x_embed | node_output | ypred | y_nodepred
    float* o_embed = (float*)d_out;
    float* o_node  = o_embed + (size_t)N * 128;
    float* o_ypred = o_node + (size_t)M * 3;
    float* o_ynode = o_ypred + (size_t)N;

    const int gemm_blocks = (N + 63) / 64;
    const int agg_blocks = (N + 7) / 8;
    const int n_blocks = (N + 255) / 256;

    // ---- 2-level CSR build (once) ----
    hipMemsetAsync(gh_d, 0, 2048 * sizeof(unsigned int), stream);
    coarse_hist<<<NBLK, 512, 0, stream>>>(ei, E, Et, gh_d, gh_s, CB);
    coarse_scan<<<1, 1024, 0, stream>>>(gh_d, gh_s, coff_d, coff_s, cur_d, cur_s,
                                        CB, (unsigned int)Et);
    coarse_scatter_both<<<NBLK, 512, 0, stream>>>(ei, E, Et, cur_d, cur_s, tmp_d, tmp_s, CB);
    fine_sort<<<2 * CB, 256, 0, stream>>>(tmp_d, tmp_s, coff_d, coff_s, off_d, off_s,
                                          srcs, dsts, N, CB, (unsigned int)Et);

    for (int L = 0; L < 3; ++L) {
        const float* hin = (L == 0) ? x : hb;
        gemm128<<<gemm_blocks, 256, 0, stream>>>(hin, W[L], att[L], xlin,
                                                 (float4*)ni, (float2*)ad, N);
        src_sum<<<n_blocks, 256, 0, stream>>>(dsts, off_s, (const float2*)ad, ni, N);
        edge_w<<<CB, 256, 0, stream>>>(srcs, off_d, (const float4*)ni, (const float2*)ad,
                                       w2, N);
        if (L < 2)
            agg_csr<false><<<agg_blocks, 512, 0, stream>>>(
                srcs, off_d, (const float2*)xlin, (const float2*)w2,
                b[L], hb, nullptr, nullptr, nullptr, nullptr, N);
        else
            agg_csr<true><<<agg_blocks, 512, 0, stream>>>(
                srcs, off_d, (const float2*)xlin, (const float2*)w2,
                b[L], o_embed, Wout, bout, out3, o_ypred, N);
    }
    gather_out<<<(M + 255) / 256, 256, 0, stream>>>(out3, o_ypred, node_index, o_node, o_ynode, M);
}